// Round 14
// baseline (580.937 us; speedup 1.0000x reference)
//
#include <hip/hip_runtime.h>
#include <math.h>

#define BB 2
#define LL 4
#define CC 128
#define HH 48
#define WWID 176
#define HW 8448   // 48*176

typedef _Float16 f16;
typedef __attribute__((ext_vector_type(8))) _Float16 f16x8;
typedef __attribute__((ext_vector_type(4))) _Float16 f16x4;
typedef __attribute__((ext_vector_type(2))) _Float16 f16x2;
typedef __attribute__((ext_vector_type(4))) float f32x4;
typedef __attribute__((ext_vector_type(4))) unsigned int u32x4;

// inverse affine from a 4x4 pairwise T block
__device__ __forceinline__ void ainv_from(const float* __restrict__ t, float* a)
{
    float R00=t[0], R01=t[1], t0=t[3];
    float R10=t[4], R11=t[5], t1=t[7];
    float tx = t0 * 0.625f;              // / (RATIO*DS) = /1.6
    float ty = t1 * 0.625f;
    const float cx = WWID/2.0f, cy = HH/2.0f;
    float ftx = cx - (R00*cx + R01*cy) + tx;
    float fty = cy - (R10*cx + R11*cy) + ty;
    float det = R00*R11 - R01*R10;
    float inv = 1.0f/det;
    float i00 =  R11*inv, i01 = -R01*inv, i10 = -R10*inv, i11 = R00*inv;
    a[0]=i00; a[1]=i01; a[2]=-(i00*ftx + i01*fty);
    a[3]=i10; a[4]=i11; a[5]=-(i10*ftx + i11*fty);
}

// ---------------------------------------------------------------------------
// prep: one dispatch doing weight repack (fragment order), x->f16 transpose,
// and fac maps.  Block-id switch; each section proven separately.
//   repack: blk=(tap*8+kq)*8+ocblk; within blk [l15 16][hi 4][j 8]
// ---------------------------------------------------------------------------
__global__ __launch_bounds__(256)
void prep_kernel(const float* __restrict__ Wm, const float* __restrict__ Wg,
                 const float* __restrict__ Wc, const float* __restrict__ x,
                 const float* __restrict__ T, const float* __restrict__ mask,
                 f16* __restrict__ WmF, f16* __restrict__ WuF, f16* __restrict__ WcF,
                 f16* __restrict__ xT, float* __restrict__ fac)
{
    int bid = blockIdx.x;
    int tid = threadIdx.x;
    if (bid < 3456) {
        int which = bid / 1152;
        const float* src = (which==0) ? Wm : (which==1) ? Wg : Wc;
        f16* dst         = (which==0) ? WmF : (which==1) ? WuF : WcF;
        int oc_off = (which==1) ? 128 : 0;
        int stride = (which==0) ? 256 : 384;
        int idx = (bid % 1152)*256 + tid;
        int j     = idx & 7;
        int hi    = (idx >> 3) & 3;
        int l15   = (idx >> 5) & 15;
        int ocblk = (idx >> 9) & 7;
        int kq    = (idx >> 12) & 7;
        int tap   = idx >> 15;
        int oc  = ocblk*16 + l15;
        int cin = kq*32 + hi*8 + j;
        dst[idx] = (f16)src[((size_t)(oc_off+oc)*stride + cin)*9 + tap];
    } else if (bid < 3720) {
        int g = bid - 3456;
        int bl = g / 33;
        int pix = (g % 33)*256 + tid;
        const float* src = x + (size_t)bl*CC*HW + pix;
        f16* dst = xT + (size_t)bl*HW*CC + (size_t)pix*CC;
        for (int gg = 0; gg < 8; ++gg) {
            f16x8 v0, v1;
            #pragma unroll
            for (int c2 = 0; c2 < 8; ++c2) {
                v0[c2] = (f16)src[(size_t)(gg*16 + c2    )*HW];
                v1[c2] = (f16)src[(size_t)(gg*16 + 8 + c2)*HW];
            }
            *(f16x8*)(dst + gg*16    ) = v0;
            *(f16x8*)(dst + gg*16 + 8) = v1;
        }
    } else {
        int g = bid - 3720;
        int slot = g / 33;                    // (b<<4)|(l2<<2)|l1
        int pix = (g % 33)*256 + tid;
        int b = slot >> 4, l2 = (slot >> 2) & 3;
        float mk = mask[b*LL + l2];
        float a[6];
        ainv_from(T + slot*16, a);
        float gx = (float)(pix % WWID), gy = (float)(pix / WWID);
        float sx = a[0]*gx + a[1]*gy + a[2];
        float sy = a[3]*gx + a[4]*gy + a[5];
        float x0 = floorf(sx), y0 = floorf(sy);
        float wx = sx-x0, wy = sy-y0;
        int xi=(int)x0, yi=(int)y0;
        bool vx0 = xi>=0 && xi<WWID, vx1 = xi+1>=0 && xi+1<WWID;
        bool vy0 = yi>=0 && yi<HH,   vy1 = yi+1>=0 && yi+1<HH;
        float r = (vx0&&vy0?(1.f-wx)*(1.f-wy):0.f) + (vx1&&vy0?wx*(1.f-wy):0.f)
                + (vx0&&vy1?(1.f-wx)*wy:0.f)       + (vx1&&vy1?wx*wy:0.f);
        fac[(size_t)slot*HW + pix] = r*mk;
    }
}

// ===========================================================================
// msg conv: z = (b, l1, src), src in 0..3.
//   src != l1: gather sender job (skip if mask[src]==0), weights cin[0:128),
//              scale fac[src slot], write slab[src].
//   src == l1: MERGED job — stage linear once; sender loop -> slab×fac_diag;
//              ego loop (cin[128:256)) -> RMW slab += (acc+bias)×facsum.
// block = 128 oc x (8y x 16x) px, 4 waves, fragment-order A, invrec folded.
// ===========================================================================
__global__ __launch_bounds__(256,3)
void msg_conv_kernel(const f16* __restrict__ featT, const float* __restrict__ T,
                     const float* __restrict__ fac, const float* __restrict__ mask,
                     const int* __restrict__ reclen,
                     const f16* __restrict__ WmF, const float* __restrict__ bm,
                     f16* __restrict__ Pm, int n_l1)
{
    int z = blockIdx.z;
    int b = z / (n_l1*4);
    int rem = z - b*(n_l1*4);
    int l1 = rem / 4, src = rem % 4;
    if (l1 != 0 && mask[b*LL + l1] == 0.f) return;   // output never consumed
    bool merged = (src == l1);
    if (!merged && mask[b*LL + src] == 0.f) return;  // sender inactive
    int l2 = src;

    int ty = blockIdx.x / 11, tx = blockIdx.x % 11;
    int y0 = ty*8, x0 = tx*16;
    int tid = threadIdx.x;
    int wid = tid >> 6, lane = tid & 63;
    int wr = wid >> 1, wc = wid & 1;
    int l15 = lane & 15, hi = lane >> 4;

    __shared__ short lt[180*128];        // 45 KB
    __shared__ float tw[4][192];
    __shared__ int   tof[4][192];

    const f16* in = featT + (size_t)(b*LL + l2)*HW*CC;

    if (!merged) {
        // per-row bilinear taps (once), then 4-tap packed-f16 blend staging
        float a6[6];
        ainv_from(T + ((b*LL + l2)*LL + l1)*16, a6);
        float a0=a6[0],a1=a6[1],a2=a6[2],a3=a6[3],a4=a6[4],a5=a6[5];
        for (int r = tid; r < 180; r += 256) {
            int yy = r / 18, xx = r - yy*18;
            int gy = y0 - 1 + yy, gx = x0 - 1 + xx;
            float w00=0.f,w10=0.f,w01=0.f,w11=0.f;
            int o00=0,o10=0,o01=0,o11=0;
            if (gy>=0 && gy<HH && gx>=0 && gx<WWID) {
                float sx = a0*(float)gx + a1*(float)gy + a2;
                float sy = a3*(float)gx + a4*(float)gy + a5;
                float xf = floorf(sx), yf = floorf(sy);
                float wx = sx-xf, wyv = sy-yf;
                int xi=(int)xf, yi=(int)yf;
                bool vx0=xi>=0&&xi<WWID, vx1=xi+1>=0&&xi+1<WWID;
                bool vy0=yi>=0&&yi<HH,   vy1=yi+1>=0&&yi+1<HH;
                int xc0=min(max(xi,0),WWID-1), xc1=min(max(xi+1,0),WWID-1);
                int yc0=min(max(yi,0),HH-1),   yc1=min(max(yi+1,0),HH-1);
                o00=(yc0*WWID+xc0)*CC; o10=(yc0*WWID+xc1)*CC;
                o01=(yc1*WWID+xc0)*CC; o11=(yc1*WWID+xc1)*CC;
                w00=(vx0&&vy0)?(1.f-wx)*(1.f-wyv):0.f;
                w10=(vx1&&vy0)?wx*(1.f-wyv):0.f;
                w01=(vx0&&vy1)?(1.f-wx)*wyv:0.f;
                w11=(vx1&&vy1)?wx*wyv:0.f;
            }
            tw[0][r]=w00; tw[1][r]=w10; tw[2][r]=w01; tw[3][r]=w11;
            tof[0][r]=o00; tof[1][r]=o10; tof[2][r]=o01; tof[3][r]=o11;
        }
        __syncthreads();
        for (int i = tid; i < 180*16; i += 256) {
            int row = i >> 4, cg = i & 15;
            f16 h00=(f16)tw[0][row], h10=(f16)tw[1][row];
            f16 h01=(f16)tw[2][row], h11=(f16)tw[3][row];
            f16x2 W00={h00,h00}, W10={h10,h10}, W01={h01,h01}, W11={h11,h11};
            int o00=tof[0][row], o10=tof[1][row], o01=tof[2][row], o11=tof[3][row];
            f16x8 t00 = *(const f16x8*)(in + o00 + cg*8);
            f16x8 t10 = *(const f16x8*)(in + o10 + cg*8);
            f16x8 t01 = *(const f16x8*)(in + o01 + cg*8);
            f16x8 t11 = *(const f16x8*)(in + o11 + cg*8);
            const f16x2* p00 = (const f16x2*)&t00;
            const f16x2* p10 = (const f16x2*)&t10;
            const f16x2* p01 = (const f16x2*)&t01;
            const f16x2* p11 = (const f16x2*)&t11;
            f16x8 outv;
            f16x2* po = (f16x2*)&outv;
            #pragma unroll
            for (int q=0;q<4;++q)
                po[q] = p00[q]*W00 + p10[q]*W10 + p01[q]*W01 + p11[q]*W11;
            int byte = row*256 + ((cg*16) ^ ((row&7)<<4));
            *(f16x8*)((char*)lt + byte) = outv;
        }
    } else {
        for (int i = tid; i < 180*16; i += 256) {
            int row = i >> 4, cg = i & 15;
            int yy = row / 18, xx = row - yy*18;
            int gy = y0 - 1 + yy, gx = x0 - 1 + xx;
            u32x4 val = {0,0,0,0};
            if (gy>=0 && gy<HH && gx>=0 && gx<WWID)
                val = *(const u32x4*)(in + (size_t)(gy*WWID+gx)*CC + cg*8);
            int byte = row*256 + ((cg*16) ^ ((row&7)<<4));
            *(u32x4*)((char*)lt + byte) = val;
        }
    }
    __syncthreads();

    float invrec = 1.0f / (float)reclen[b];
    const f16* wlane = WmF + l15*32 + hi*8;
    f16* outp = Pm + ((size_t)(b*n_l1 + l1)*4 + src)*HW*CC;

    int npass = merged ? 2 : 1;
    for (int pass = 0; pass < npass; ++pass) {
        bool ego = merged && (pass == 1);

        f32x4 acc[4][4];
        #pragma unroll
        for (int m=0;m<4;++m)
            #pragma unroll
            for (int n=0;n<4;++n) acc[m][n] = (f32x4){0.f,0.f,0.f,0.f};

        const int kqbase = ego ? 4 : 0;
        __builtin_amdgcn_s_setprio(1);
        for (int tap=0; tap<9; ++tap) {
            int dy = tap/3, dx = tap - dy*3;
            #pragma unroll
            for (int kk=0; kk<4; ++kk) {
                const f16* wt = wlane + (size_t)(((tap*8 + kqbase + kk)*8 + wr*4))*512;
                f16x8 av[4];
                #pragma unroll
                for (int m=0;m<4;++m)
                    av[m] = *(const f16x8*)(wt + m*512);
                f16x8 bv[4];
                #pragma unroll
                for (int n=0;n<4;++n) {
                    int pos = (wc*4 + n + dy)*18 + dx + l15;
                    int byte = pos*256 + ((kk*64 + hi*16) ^ ((pos&7)<<4));
                    bv[n] = *(const f16x8*)((const char*)lt + byte);
                }
                #pragma unroll
                for (int m=0;m<4;++m)
                    #pragma unroll
                    for (int n=0;n<4;++n)
                        acc[m][n] = __builtin_amdgcn_mfma_f32_16x16x32_f16(
                            av[m], bv[n], acc[m][n], 0, 0, 0);
            }
        }
        __builtin_amdgcn_s_setprio(0);

        // per-pixel scale for this pass
        float fsc[4];
        if (ego) {
            #pragma unroll
            for (int n=0;n<4;++n) fsc[n] = 0.f;
            for (int j=0;j<LL;++j) {
                if (mask[b*LL + j] == 0.f) continue;
                const float* fp = fac + (size_t)(b*16 + j*4 + l1)*HW;
                #pragma unroll
                for (int n=0;n<4;++n)
                    fsc[n] += fp[(y0 + wc*4 + n)*WWID + x0 + l15];
            }
        } else {
            const float* fp = fac + (size_t)(b*16 + l2*4 + l1)*HW;
            #pragma unroll
            for (int n=0;n<4;++n)
                fsc[n] = fp[(y0 + wc*4 + n)*WWID + x0 + l15];
        }
        #pragma unroll
        for (int n=0;n<4;++n) fsc[n] *= invrec;

        #pragma unroll
        for (int m=0;m<4;++m) {
            f32x4 b4 = {0.f,0.f,0.f,0.f};
            if (ego) b4 = *(const f32x4*)(bm + wr*64 + m*16 + hi*4);
            #pragma unroll
            for (int n=0;n<4;++n) {
                int pix = (y0 + wc*4 + n)*WWID + x0 + l15;
                int oc  = wr*64 + m*16 + hi*4;
                f32x4 v = (acc[m][n] + b4) * fsc[n];
                f16x4 h;
                if (ego) {
                    f16x4 prev = *(const f16x4*)(outp + (size_t)pix*CC + oc);
                    #pragma unroll
                    for (int j=0;j<4;++j) h[j] = (f16)((float)prev[j] + v[j]);
                } else {
                    h[0]=(f16)v[0]; h[1]=(f16)v[1]; h[2]=(f16)v[2]; h[3]=(f16)v[3];
                }
                *(f16x4*)(outp + (size_t)pix*CC + oc) = h;
            }
        }
    }
}

// ===========================================================================
// gru conv (both gates via blockIdx.y, reduce FOLDED into s==1 staging):
// stage feat; MFMA; stage sum-of-4-Pm-slabs; MFMA.  acc[4][4], fragment A.
// Raw conv -> f16 slab Pg[gate][z]; activation in combine_kernel.
// ===========================================================================
__global__ __launch_bounds__(256,3)
void gru_conv_kernel(const f16* __restrict__ featT, const f16* __restrict__ Pm,
                     const float* __restrict__ mask,
                     const f16* __restrict__ WuF, const f16* __restrict__ WcF,
                     f16* __restrict__ Pg, int n_l1)
{
    int z = blockIdx.z;
    int b = z / n_l1, l1 = z % n_l1;
    if (l1 != 0 && mask[b*LL + l1] == 0.f) return;
    int gate = blockIdx.y;               // 0 = U, 1 = C (block-uniform)

    int ty = blockIdx.x / 11, tx = blockIdx.x % 11;
    int y0 = ty*8, x0 = tx*16;
    int tid = threadIdx.x;
    int wid = tid >> 6, lane = tid & 63;
    int wr = wid >> 1, wc = wid & 1;
    int l15 = lane & 15, hi = lane >> 4;

    __shared__ short lt[180*128];  // 45 KB

    f32x4 acc[4][4];
    #pragma unroll
    for (int m=0;m<4;++m)
        #pragma unroll
        for (int n=0;n<4;++n) acc[m][n] = (f32x4){0.f,0.f,0.f,0.f};

    const f16* WF = (gate==0) ? WuF : WcF;
    const f16* wlane = WF + l15*32 + hi*8;

    bool act[4];
    #pragma unroll
    for (int j=0;j<LL;++j)
        act[j] = (j == l1) || (mask[b*LL + j] != 0.f);
    const f16* pmbase = Pm + (size_t)((b*n_l1 + l1)*4)*HW*CC;

    for (int s = 0; s < 2; ++s) {
        if (s) __syncthreads();           // MFMA readers of stage-0 done
        if (s == 0) {
            const f16* in = featT + (size_t)(b*LL + l1)*HW*CC;
            for (int i = tid; i < 180*16; i += 256) {
                int row = i >> 4, cg = i & 15;
                int yy = row / 18, xx = row - yy*18;
                int gy = y0 - 1 + yy, gx = x0 - 1 + xx;
                u32x4 val = {0,0,0,0};
                if (gy>=0 && gy<HH && gx>=0 && gx<WWID)
                    val = *(const u32x4*)(in + (size_t)(gy*WWID+gx)*CC + cg*8);
                int byte = row*256 + ((cg*16) ^ ((row&7)<<4));
                *(u32x4*)((char*)lt + byte) = val;
            }
        } else {
            // agg = sum of active Pm slabs (invrec pre-folded by msg)
            for (int i = tid; i < 180*16; i += 256) {
                int row = i >> 4, cg = i & 15;
                int yy = row / 18, xx = row - yy*18;
                int gy = y0 - 1 + yy, gx = x0 - 1 + xx;
                f16x8 o = {0,0,0,0,0,0,0,0};
                if (gy>=0 && gy<HH && gx>=0 && gx<WWID) {
                    size_t off = (size_t)(gy*WWID+gx)*CC + cg*8;
                    float sacc[8];
                    f16x8 p0 = *(const f16x8*)(pmbase + (size_t)l1*HW*CC + off);
                    #pragma unroll
                    for (int j8=0;j8<8;++j8) sacc[j8] = (float)p0[j8];
                    #pragma unroll
                    for (int j=0;j<LL;++j) {
                        if (j == l1 || !act[j]) continue;
                        f16x8 p = *(const f16x8*)(pmbase + (size_t)j*HW*CC + off);
                        #pragma unroll
                        for (int j8=0;j8<8;++j8) sacc[j8] += (float)p[j8];
                    }
                    #pragma unroll
                    for (int j8=0;j8<8;++j8) o[j8] = (f16)sacc[j8];
                }
                int byte = row*256 + ((cg*16) ^ ((row&7)<<4));
                *(f16x8*)((char*)lt + byte) = o;
            }
        }
        __syncthreads();

        int kqbase = s*4;
        __builtin_amdgcn_s_setprio(1);
        for (int tap=0; tap<9; ++tap) {
            int dy = tap/3, dx = tap - dy*3;
            #pragma unroll
            for (int kk=0; kk<4; ++kk) {
                const f16* wt = wlane + (size_t)(((tap*8 + kqbase + kk)*8 + wr*4))*512;
                f16x8 av[4];
                #pragma unroll
                for (int m=0;m<4;++m)
                    av[m] = *(const f16x8*)(wt + m*512);
                f16x8 bv[4];
                #pragma unroll
                for (int n=0;n<4;++n) {
                    int pos = (wc*4 + n + dy)*18 + dx + l15;
                    int byte = pos*256 + ((kk*64 + hi*16) ^ ((pos&7)<<4));
                    bv[n] = *(const f16x8*)((const char*)lt + byte);
                }
                #pragma unroll
                for (int m=0;m<4;++m)
                    #pragma unroll
                    for (int n=0;n<4;++n)
                        acc[m][n] = __builtin_amdgcn_mfma_f32_16x16x32_f16(
                            av[m], bv[n], acc[m][n], 0, 0, 0);
            }
        }
        __builtin_amdgcn_s_setprio(0);
    }

    f16* outp = Pg + ((size_t)(gate*(BB*LL) + z))*HW*CC;
    #pragma unroll
    for (int m=0;m<4;++m)
        #pragma unroll
        for (int n=0;n<4;++n) {
            int pix = (y0 + wc*4 + n)*WWID + x0 + l15;
            int oc  = wr*64 + m*16 + hi*4;
            f32x4 v = acc[m][n];
            f16x4 h = {(f16)v[0], (f16)v[1], (f16)v[2], (f16)v[3]};
            *(f16x4*)(outp + (size_t)pix*CC + oc) = h;
        }
}

// ---------------------------------------------------------------------------
// combine: h = sigmoid(U+bgU) * tanh(C+bc) -> f16 [z][pix][ch]
// ---------------------------------------------------------------------------
__global__ __launch_bounds__(256)
void combine_kernel(const f16* __restrict__ Pg, const float* __restrict__ mask,
                    const float* __restrict__ bgU, const float* __restrict__ bc,
                    f16* __restrict__ outT, int n_l1)
{
    int z = blockIdx.y;
    int b = z / n_l1, l1 = z % n_l1;
    if (l1 != 0 && mask[b*LL + l1] == 0.f) return;
    int pix = blockIdx.x*256 + threadIdx.x;
    size_t poff = (size_t)pix*CC;
    const f16* U = Pg + ((size_t)(0*(BB*LL) + z))*HW*CC + poff;
    const f16* C = Pg + ((size_t)(1*(BB*LL) + z))*HW*CC + poff;
    f16* dst = outT + (size_t)z*HW*CC + poff;
    for (int cg=0; cg<16; ++cg) {
        f16x8 u8 = *(const f16x8*)(U + cg*8);
        f16x8 c8 = *(const f16x8*)(C + cg*8);
        f16x8 o;
        #pragma unroll
        for (int j=0; j<8; ++j) {
            float uu = (float)u8[j] + bgU[cg*8 + j];
            float cc = (float)c8[j] + bc[cg*8 + j];
            float sig = 1.f/(1.f + expf(-uu));
            o[j] = (f16)(sig * tanhf(cc));
        }
        *(f16x8*)(dst + cg*8) = o;
    }
}

// ---------------------------------------------------------------------------
// final 1x1 MLP:  out[b][oc][pix] = sum_c feat2T[b][pix][c]*W[oc][c] + bias
// ---------------------------------------------------------------------------
__global__ __launch_bounds__(256)
void mlp_kernel(const f16* __restrict__ feat2T, const float* __restrict__ Wm,
                const float* __restrict__ bmlp, float* __restrict__ out)
{
    int b = blockIdx.z, oc0 = blockIdx.y*32;
    int pix = blockIdx.x*256 + threadIdx.x;
    const f16* src = feat2T + (size_t)b*HW*CC + (size_t)pix*CC;
    float acc[32];
    #pragma unroll
    for (int oc=0;oc<32;++oc) acc[oc]=0.f;
    for (int c8 = 0; c8 < 16; ++c8) {
        f16x8 v = *(const f16x8*)(src + c8*8);
        float f[8];
        #pragma unroll
        for (int j=0;j<8;++j) f[j] = (float)v[j];
        #pragma unroll
        for (int oc=0; oc<32; ++oc) {
            const float* w = Wm + (size_t)(oc0+oc)*CC + c8*8;
            #pragma unroll
            for (int j=0;j<8;++j) acc[oc] = fmaf(f[j], w[j], acc[oc]);
        }
    }
    #pragma unroll
    for (int oc=0;oc<32;++oc)
        out[((size_t)b*CC + oc0+oc)*HW + pix] = acc[oc] + bmlp[oc0+oc];
}

// ---------------------------------------------------------------------------
extern "C" void kernel_launch(void* const* d_in, const int* in_sizes, int n_in,
                              void* d_out, int out_size, void* d_ws, size_t ws_size,
                              hipStream_t stream)
{
    const float* x     = (const float*)d_in[0];
    const float* mask  = (const float*)d_in[1];
    const float* T     = (const float*)d_in[2];
    const int*   recl  = (const int*)  d_in[3];
    const float* Wmsg  = (const float*)d_in[4];
    const float* bmsg  = (const float*)d_in[5];
    const float* Wg    = (const float*)d_in[6];
    const float* bg    = (const float*)d_in[7];
    const float* Wc    = (const float*)d_in[8];
    const float* bc    = (const float*)d_in[9];
    const float* Wmlp  = (const float*)d_in[10];
    const float* bmlp  = (const float*)d_in[11];
    float* out = (float*)d_out;

    char* w = (char*)d_ws;
    f16*   xT   = (f16*)w;            w += (size_t)BB*LL*HW*CC*2;      // 17.3 MB
    float* fac  = (float*)w;          w += (size_t)32*HW*4;            // 1.1 MB
    f16*   WmF  = (f16*)w;            w += (size_t)9*128*256*2;
    f16*   WuF  = (f16*)w;            w += (size_t)9*128*256*2;
    f16*   WcF  = (f16*)w;            w += (size_t)9*128*256*2;
    f16*   Pm   = (f16*)w;            w += (size_t)32*HW*CC*2;         // 69.2 MB
    f16*   Pg   = (f16*)w;            w += (size_t)2*BB*LL*HW*CC*2;    // 34.6 MB
    f16*   f1T  = (f16*)w;            w += (size_t)BB*LL*HW*CC*2;      // 17.3 MB
    f16*   f2T  = (f16*)w;            w += (size_t)BB*HW*CC*2;         // 4.3 MB

    prep_kernel<<<4776, 256, 0, stream>>>(Wmsg, Wg, Wc, x, T, mask,
                                          WmF, WuF, WcF, xT, fac);

    // ---- iteration 1 ----
    msg_conv_kernel<<<dim3(66, 1, BB*LL*4), 256, 0, stream>>>(
        xT, T, fac, mask, recl, WmF, bmsg, Pm, LL);
    gru_conv_kernel<<<dim3(66, 2, BB*LL), 256, 0, stream>>>(
        xT, Pm, mask, WuF, WcF, Pg, LL);
    combine_kernel<<<dim3(33, BB*LL), 256, 0, stream>>>(
        Pg, mask, bg + CC, bc, f1T, LL);

    // ---- iteration 2 (only l1=0 consumed) ----
    msg_conv_kernel<<<dim3(66, 1, BB*4), 256, 0, stream>>>(
        f1T, T, fac, mask, recl, WmF, bmsg, Pm, 1);
    gru_conv_kernel<<<dim3(66, 2, BB), 256, 0, stream>>>(
        f1T, Pm, mask, WuF, WcF, Pg, 1);
    combine_kernel<<<dim3(33, BB), 256, 0, stream>>>(
        Pg, mask, bg + CC, bc, f2T, 1);

    // ---- final MLP ----
    mlp_kernel<<<dim3(33, 4, BB), 256, 0, stream>>>(f2T, Wmlp, bmlp, out);
}

// Round 16
// 503.987 us; speedup vs baseline: 1.1527x; 1.1527x over previous
//
#include <hip/hip_runtime.h>
#include <math.h>

#define BB 2
#define LL 4
#define CC 128
#define HH 48
#define WWID 176
#define HW 8448   // 48*176

typedef _Float16 f16;
typedef __attribute__((ext_vector_type(8))) _Float16 f16x8;
typedef __attribute__((ext_vector_type(4))) _Float16 f16x4;
typedef __attribute__((ext_vector_type(2))) _Float16 f16x2;
typedef __attribute__((ext_vector_type(4))) float f32x4;
typedef __attribute__((ext_vector_type(4))) unsigned int u32x4;

// inverse affine from a 4x4 pairwise T block
__device__ __forceinline__ void ainv_from(const float* __restrict__ t, float* a)
{
    float R00=t[0], R01=t[1], t0=t[3];
    float R10=t[4], R11=t[5], t1=t[7];
    float tx = t0 * 0.625f;              // / (RATIO*DS) = /1.6
    float ty = t1 * 0.625f;
    const float cx = WWID/2.0f, cy = HH/2.0f;
    float ftx = cx - (R00*cx + R01*cy) + tx;
    float fty = cy - (R10*cx + R11*cy) + ty;
    float det = R00*R11 - R01*R10;
    float inv = 1.0f/det;
    float i00 =  R11*inv, i01 = -R01*inv, i10 = -R10*inv, i11 = R00*inv;
    a[0]=i00; a[1]=i01; a[2]=-(i00*ftx + i01*fty);
    a[3]=i10; a[4]=i11; a[5]=-(i10*ftx + i11*fty);
}

// ---------------------------------------------------------------------------
// prep: one dispatch doing weight repack (fragment order), x->f16 transpose,
// and fac maps.  Block-id switch; each section proven separately.
//   repack: blk=(tap*8+kq)*8+ocblk; within blk [l15 16][hi 4][j 8]
// ---------------------------------------------------------------------------
__global__ __launch_bounds__(256)
void prep_kernel(const float* __restrict__ Wm, const float* __restrict__ Wg,
                 const float* __restrict__ Wc, const float* __restrict__ x,
                 const float* __restrict__ T, const float* __restrict__ mask,
                 f16* __restrict__ WmF, f16* __restrict__ WuF, f16* __restrict__ WcF,
                 f16* __restrict__ xT, float* __restrict__ fac)
{
    int bid = blockIdx.x;
    int tid = threadIdx.x;
    if (bid < 3456) {
        int which = bid / 1152;
        const float* src = (which==0) ? Wm : (which==1) ? Wg : Wc;
        f16* dst         = (which==0) ? WmF : (which==1) ? WuF : WcF;
        int oc_off = (which==1) ? 128 : 0;
        int stride = (which==0) ? 256 : 384;
        int idx = (bid % 1152)*256 + tid;
        int j     = idx & 7;
        int hi    = (idx >> 3) & 3;
        int l15   = (idx >> 5) & 15;
        int ocblk = (idx >> 9) & 7;
        int kq    = (idx >> 12) & 7;
        int tap   = idx >> 15;
        int oc  = ocblk*16 + l15;
        int cin = kq*32 + hi*8 + j;
        dst[idx] = (f16)src[((size_t)(oc_off+oc)*stride + cin)*9 + tap];
    } else if (bid < 3720) {
        int g = bid - 3456;
        int bl = g / 33;
        int pix = (g % 33)*256 + tid;
        const float* src = x + (size_t)bl*CC*HW + pix;
        f16* dst = xT + (size_t)bl*HW*CC + (size_t)pix*CC;
        for (int gg = 0; gg < 8; ++gg) {
            f16x8 v0, v1;
            #pragma unroll
            for (int c2 = 0; c2 < 8; ++c2) {
                v0[c2] = (f16)src[(size_t)(gg*16 + c2    )*HW];
                v1[c2] = (f16)src[(size_t)(gg*16 + 8 + c2)*HW];
            }
            *(f16x8*)(dst + gg*16    ) = v0;
            *(f16x8*)(dst + gg*16 + 8) = v1;
        }
    } else {
        int g = bid - 3720;
        int slot = g / 33;                    // (b<<4)|(l2<<2)|l1
        int pix = (g % 33)*256 + tid;
        int b = slot >> 4, l2 = (slot >> 2) & 3;
        float mk = mask[b*LL + l2];
        float a[6];
        ainv_from(T + slot*16, a);
        float gx = (float)(pix % WWID), gy = (float)(pix / WWID);
        float sx = a[0]*gx + a[1]*gy + a[2];
        float sy = a[3]*gx + a[4]*gy + a[5];
        float x0 = floorf(sx), y0 = floorf(sy);
        float wx = sx-x0, wy = sy-y0;
        int xi=(int)x0, yi=(int)y0;
        bool vx0 = xi>=0 && xi<WWID, vx1 = xi+1>=0 && xi+1<WWID;
        bool vy0 = yi>=0 && yi<HH,   vy1 = yi+1>=0 && yi+1<HH;
        float r = (vx0&&vy0?(1.f-wx)*(1.f-wy):0.f) + (vx1&&vy0?wx*(1.f-wy):0.f)
                + (vx0&&vy1?(1.f-wx)*wy:0.f)       + (vx1&&vy1?wx*wy:0.f);
        fac[(size_t)slot*HW + pix] = r*mk;
    }
}

// ===========================================================================
// msg conv (round-13, proven): one JOB per block-z: z = (b, l1, src).
// src<4: sender l2=src (gather unless l2==l1), weights cin[0:128),
// scale fac[l2 slot]; src==4: ego, weights cin[128:256), scale facsum, +bias.
// block = 128 oc x (8y x 16x) px, 4 waves, fragment-order A, pk-f16 blend.
// Output fp16 Pm[z][pix][oc] (fac/bias/invrec folded).
// ===========================================================================
__global__ __launch_bounds__(256,3)
void msg_conv_kernel(const f16* __restrict__ featT, const float* __restrict__ T,
                     const float* __restrict__ fac, const float* __restrict__ mask,
                     const int* __restrict__ reclen,
                     const f16* __restrict__ WmF, const float* __restrict__ bm,
                     f16* __restrict__ Pm, int n_l1)
{
    int z = blockIdx.z;
    int b = z / (n_l1*5);
    int rem = z - b*(n_l1*5);
    int l1 = rem / 5, src = rem % 5;
    if (l1 != 0 && mask[b*LL + l1] == 0.f) return;   // output never consumed
    bool ego = (src == 4);
    int l2 = ego ? l1 : src;
    if (!ego && mask[b*LL + l2] == 0.f) return;      // sender inactive
    bool gather = (!ego) && (l2 != l1);

    int ty = blockIdx.x / 11, tx = blockIdx.x % 11;
    int y0 = ty*8, x0 = tx*16;
    int tid = threadIdx.x;
    int wid = tid >> 6, lane = tid & 63;
    int wr = wid >> 1, wc = wid & 1;
    int l15 = lane & 15, hi = lane >> 4;

    __shared__ short lt[180*128];        // 45 KB
    __shared__ float tw[4][192];
    __shared__ int   tof[4][192];

    const f16* in = featT + (size_t)(b*LL + l2)*HW*CC;

    if (gather) {
        // per-row bilinear taps (once), then 4-tap packed-f16 blend staging
        float a6[6];
        ainv_from(T + ((b*LL + l2)*LL + l1)*16, a6);
        float a0=a6[0],a1=a6[1],a2=a6[2],a3=a6[3],a4=a6[4],a5=a6[5];
        for (int r = tid; r < 180; r += 256) {
            int yy = r / 18, xx = r - yy*18;
            int gy = y0 - 1 + yy, gx = x0 - 1 + xx;
            float w00=0.f,w10=0.f,w01=0.f,w11=0.f;
            int o00=0,o10=0,o01=0,o11=0;
            if (gy>=0 && gy<HH && gx>=0 && gx<WWID) {
                float sx = a0*(float)gx + a1*(float)gy + a2;
                float sy = a3*(float)gx + a4*(float)gy + a5;
                float xf = floorf(sx), yf = floorf(sy);
                float wx = sx-xf, wyv = sy-yf;
                int xi=(int)xf, yi=(int)yf;
                bool vx0=xi>=0&&xi<WWID, vx1=xi+1>=0&&xi+1<WWID;
                bool vy0=yi>=0&&yi<HH,   vy1=yi+1>=0&&yi+1<HH;
                int xc0=min(max(xi,0),WWID-1), xc1=min(max(xi+1,0),WWID-1);
                int yc0=min(max(yi,0),HH-1),   yc1=min(max(yi+1,0),HH-1);
                o00=(yc0*WWID+xc0)*CC; o10=(yc0*WWID+xc1)*CC;
                o01=(yc1*WWID+xc0)*CC; o11=(yc1*WWID+xc1)*CC;
                w00=(vx0&&vy0)?(1.f-wx)*(1.f-wyv):0.f;
                w10=(vx1&&vy0)?wx*(1.f-wyv):0.f;
                w01=(vx0&&vy1)?(1.f-wx)*wyv:0.f;
                w11=(vx1&&vy1)?wx*wyv:0.f;
            }
            tw[0][r]=w00; tw[1][r]=w10; tw[2][r]=w01; tw[3][r]=w11;
            tof[0][r]=o00; tof[1][r]=o10; tof[2][r]=o01; tof[3][r]=o11;
        }
        __syncthreads();
        for (int i = tid; i < 180*16; i += 256) {
            int row = i >> 4, cg = i & 15;
            f16 h00=(f16)tw[0][row], h10=(f16)tw[1][row];
            f16 h01=(f16)tw[2][row], h11=(f16)tw[3][row];
            f16x2 W00={h00,h00}, W10={h10,h10}, W01={h01,h01}, W11={h11,h11};
            int o00=tof[0][row], o10=tof[1][row], o01=tof[2][row], o11=tof[3][row];
            f16x8 t00 = *(const f16x8*)(in + o00 + cg*8);
            f16x8 t10 = *(const f16x8*)(in + o10 + cg*8);
            f16x8 t01 = *(const f16x8*)(in + o01 + cg*8);
            f16x8 t11 = *(const f16x8*)(in + o11 + cg*8);
            const f16x2* p00 = (const f16x2*)&t00;
            const f16x2* p10 = (const f16x2*)&t10;
            const f16x2* p01 = (const f16x2*)&t01;
            const f16x2* p11 = (const f16x2*)&t11;
            f16x8 outv;
            f16x2* po = (f16x2*)&outv;
            #pragma unroll
            for (int q=0;q<4;++q)
                po[q] = p00[q]*W00 + p10[q]*W10 + p01[q]*W01 + p11[q]*W11;
            int byte = row*256 + ((cg*16) ^ ((row&7)<<4));
            *(f16x8*)((char*)lt + byte) = outv;
        }
    } else {
        for (int i = tid; i < 180*16; i += 256) {
            int row = i >> 4, cg = i & 15;
            int yy = row / 18, xx = row - yy*18;
            int gy = y0 - 1 + yy, gx = x0 - 1 + xx;
            u32x4 val = {0,0,0,0};
            if (gy>=0 && gy<HH && gx>=0 && gx<WWID)
                val = *(const u32x4*)(in + (size_t)(gy*WWID+gx)*CC + cg*8);
            int byte = row*256 + ((cg*16) ^ ((row&7)<<4));
            *(u32x4*)((char*)lt + byte) = val;
        }
    }
    __syncthreads();

    f32x4 acc[4][4];
    #pragma unroll
    for (int m=0;m<4;++m)
        #pragma unroll
        for (int n=0;n<4;++n) acc[m][n] = (f32x4){0.f,0.f,0.f,0.f};

    const int kqbase = ego ? 4 : 0;
    const f16* wlane = WmF + l15*32 + hi*8;
    __builtin_amdgcn_s_setprio(1);
    for (int tap=0; tap<9; ++tap) {
        int dy = tap/3, dx = tap - dy*3;
        #pragma unroll
        for (int kk=0; kk<4; ++kk) {
            const f16* wt = wlane + (size_t)(((tap*8 + kqbase + kk)*8 + wr*4))*512;
            f16x8 av[4];
            #pragma unroll
            for (int m=0;m<4;++m)
                av[m] = *(const f16x8*)(wt + m*512);
            f16x8 bv[4];
            #pragma unroll
            for (int n=0;n<4;++n) {
                int pos = (wc*4 + n + dy)*18 + dx + l15;
                int byte = pos*256 + ((kk*64 + hi*16) ^ ((pos&7)<<4));
                bv[n] = *(const f16x8*)((const char*)lt + byte);
            }
            #pragma unroll
            for (int m=0;m<4;++m)
                #pragma unroll
                for (int n=0;n<4;++n)
                    acc[m][n] = __builtin_amdgcn_mfma_f32_16x16x32_f16(
                        av[m], bv[n], acc[m][n], 0, 0, 0);
        }
    }
    __builtin_amdgcn_s_setprio(0);

    // per-pixel scale: fac (pair) or facsum (ego), times invrec (precision)
    float invrec = 1.0f / (float)reclen[b];
    float fsc[4];
    if (ego) {
        #pragma unroll
        for (int n=0;n<4;++n) fsc[n] = 0.f;
        for (int j=0;j<LL;++j) {
            if (mask[b*LL + j] == 0.f) continue;
            const float* fp = fac + (size_t)(b*16 + j*4 + l1)*HW;
            #pragma unroll
            for (int n=0;n<4;++n)
                fsc[n] += fp[(y0 + wc*4 + n)*WWID + x0 + l15];
        }
    } else {
        const float* fp = fac + (size_t)(b*16 + l2*4 + l1)*HW;
        #pragma unroll
        for (int n=0;n<4;++n)
            fsc[n] = fp[(y0 + wc*4 + n)*WWID + x0 + l15];
    }
    #pragma unroll
    for (int n=0;n<4;++n) fsc[n] *= invrec;

    f16* outp = Pm + (size_t)z*HW*CC;
    #pragma unroll
    for (int m=0;m<4;++m) {
        f32x4 b4 = {0.f,0.f,0.f,0.f};
        if (ego) b4 = *(const f32x4*)(bm + wr*64 + m*16 + hi*4);
        #pragma unroll
        for (int n=0;n<4;++n) {
            int pix = (y0 + wc*4 + n)*WWID + x0 + l15;
            int oc  = wr*64 + m*16 + hi*4;
            f32x4 v = (acc[m][n] + b4) * fsc[n];
            f16x4 h = {(f16)v[0], (f16)v[1], (f16)v[2], (f16)v[3]};
            *(f16x4*)(outp + (size_t)pix*CC + oc) = h;
        }
    }
}

// ---------------------------------------------------------------------------
// reduce: aggT[zi][pix][c] f16 = sum of active job slabs (invrec pre-folded)
// ---------------------------------------------------------------------------
__global__ __launch_bounds__(256)
void reduce_agg_kernel(const f16* __restrict__ Pm, const float* __restrict__ mask,
                       f16* __restrict__ aggT, int n_l1)
{
    int zi = blockIdx.y;                 // b*n_l1 + l1
    int b = zi / n_l1, l1 = zi % n_l1;
    if (l1 != 0 && mask[b*LL + l1] == 0.f) return;
    int pix = blockIdx.x*256 + threadIdx.x;
    bool act[4];
    #pragma unroll
    for (int j=0;j<LL;++j) act[j] = (mask[b*LL + j] != 0.f);
    const f16* base = Pm + (size_t)(zi*5)*HW*CC + (size_t)pix*CC;
    f16* dst = aggT + (size_t)zi*HW*CC + (size_t)pix*CC;
    for (int cg=0; cg<16; ++cg) {
        float s[8];
        f16x8 e = *(const f16x8*)(base + (size_t)4*HW*CC + cg*8);
        #pragma unroll
        for (int j8=0;j8<8;++j8) s[j8] = (float)e[j8];
        #pragma unroll
        for (int j=0;j<4;++j) {
            if (!act[j]) continue;
            f16x8 p = *(const f16x8*)(base + (size_t)j*HW*CC + cg*8);
            #pragma unroll
            for (int j8=0;j8<8;++j8) s[j8] += (float)p[j8];
        }
        f16x8 o;
        #pragma unroll
        for (int j8=0;j8<8;++j8) o[j8] = (f16)s[j8];
        *(f16x8*)(dst + cg*8) = o;
    }
}

// ===========================================================================
// gru conv (round-13, proven): both gates via blockIdx.y.  Full K=256 per
// block (stage feat; MFMA; stage agg; MFMA), acc[4][4], fragment-order A.
// Raw conv -> f16 slab Pg[gate][z]; activation applied later.
// ===========================================================================
__global__ __launch_bounds__(256,3)
void gru_conv_kernel(const f16* __restrict__ featT, const f16* __restrict__ aggT,
                     const float* __restrict__ mask,
                     const f16* __restrict__ WuF, const f16* __restrict__ WcF,
                     f16* __restrict__ Pg, int n_l1)
{
    int z = blockIdx.z;
    int b = z / n_l1, l1 = z % n_l1;
    if (l1 != 0 && mask[b*LL + l1] == 0.f) return;
    int gate = blockIdx.y;               // 0 = U, 1 = C (block-uniform)

    int ty = blockIdx.x / 11, tx = blockIdx.x % 11;
    int y0 = ty*8, x0 = tx*16;
    int tid = threadIdx.x;
    int wid = tid >> 6, lane = tid & 63;
    int wr = wid >> 1, wc = wid & 1;
    int l15 = lane & 15, hi = lane >> 4;

    __shared__ short lt[180*128];  // 45 KB

    f32x4 acc[4][4];
    #pragma unroll
    for (int m=0;m<4;++m)
        #pragma unroll
        for (int n=0;n<4;++n) acc[m][n] = (f32x4){0.f,0.f,0.f,0.f};

    const f16* WF = (gate==0) ? WuF : WcF;
    const f16* wlane = WF + l15*32 + hi*8;

    for (int s = 0; s < 2; ++s) {
        const f16* in = (s==0) ? featT + (size_t)(b*LL + l1)*HW*CC
                               : aggT  + (size_t)(b*n_l1 + l1)*HW*CC;
        if (s) __syncthreads();           // MFMA readers of stage-0 done
        for (int i = tid; i < 180*16; i += 256) {
            int row = i >> 4, cg = i & 15;
            int yy = row / 18, xx = row - yy*18;
            int gy = y0 - 1 + yy, gx = x0 - 1 + xx;
            u32x4 val = {0,0,0,0};
            if (gy>=0 && gy<HH && gx>=0 && gx<WWID)
                val = *(const u32x4*)(in + (size_t)(gy*WWID+gx)*CC + cg*8);
            int byte = row*256 + ((cg*16) ^ ((row&7)<<4));
            *(u32x4*)((char*)lt + byte) = val;
        }
        __syncthreads();

        int kqbase = s*4;
        __builtin_amdgcn_s_setprio(1);
        for (int tap=0; tap<9; ++tap) {
            int dy = tap/3, dx = tap - dy*3;
            #pragma unroll
            for (int kk=0; kk<4; ++kk) {
                const f16* wt = wlane + (size_t)(((tap*8 + kqbase + kk)*8 + wr*4))*512;
                f16x8 av[4];
                #pragma unroll
                for (int m=0;m<4;++m)
                    av[m] = *(const f16x8*)(wt + m*512);
                f16x8 bv[4];
                #pragma unroll
                for (int n=0;n<4;++n) {
                    int pos = (wc*4 + n + dy)*18 + dx + l15;
                    int byte = pos*256 + ((kk*64 + hi*16) ^ ((pos&7)<<4));
                    bv[n] = *(const f16x8*)((const char*)lt + byte);
                }
                #pragma unroll
                for (int m=0;m<4;++m)
                    #pragma unroll
                    for (int n=0;n<4;++n)
                        acc[m][n] = __builtin_amdgcn_mfma_f32_16x16x32_f16(
                            av[m], bv[n], acc[m][n], 0, 0, 0);
            }
        }
        __builtin_amdgcn_s_setprio(0);
    }

    f16* outp = Pg + ((size_t)(gate*(BB*LL) + z))*HW*CC;
    #pragma unroll
    for (int m=0;m<4;++m)
        #pragma unroll
        for (int n=0;n<4;++n) {
            int pix = (y0 + wc*4 + n)*WWID + x0 + l15;
            int oc  = wr*64 + m*16 + hi*4;
            f32x4 v = acc[m][n];
            f16x4 h = {(f16)v[0], (f16)v[1], (f16)v[2], (f16)v[3]};
            *(f16x4*)(outp + (size_t)pix*CC + oc) = h;
        }
}

// ---------------------------------------------------------------------------
// combine: h = sigmoid(U+bgU) * tanh(C+bc) -> f16 [z][pix][ch]  (iter 1)
// ---------------------------------------------------------------------------
__global__ __launch_bounds__(256)
void combine_kernel(const f16* __restrict__ Pg, const float* __restrict__ mask,
                    const float* __restrict__ bgU, const float* __restrict__ bc,
                    f16* __restrict__ outT, int n_l1)
{
    int z = blockIdx.y;
    int b = z / n_l1, l1 = z % n_l1;
    if (l1 != 0 && mask[b*LL + l1] == 0.f) return;
    int pix = blockIdx.x*256 + threadIdx.x;
    size_t poff = (size_t)pix*CC;
    const f16* U = Pg + ((size_t)(0*(BB*LL) + z))*HW*CC + poff;
    const f16* C = Pg + ((size_t)(1*(BB*LL) + z))*HW*CC + poff;
    f16* dst = outT + (size_t)z*HW*CC + poff;
    for (int cg=0; cg<16; ++cg) {
        f16x8 u8 = *(const f16x8*)(U + cg*8);
        f16x8 c8 = *(const f16x8*)(C + cg*8);
        f16x8 o;
        #pragma unroll
        for (int j=0; j<8; ++j) {
            float uu = (float)u8[j] + bgU[cg*8 + j];
            float cc = (float)c8[j] + bc[cg*8 + j];
            float sig = 1.f/(1.f + expf(-uu));
            o[j] = (f16)(sig * tanhf(cc));
        }
        *(f16x8*)(dst + cg*8) = o;
    }
}

// ---------------------------------------------------------------------------
// mlp+combine (iter 2): h = sigmoid(U+bgU)*tanh(C+bc) computed inline from
// the gate slabs (z = b since n_l1==1; C-gate slab lives at BB*LL + b),
// then out[b][oc][pix] = W h + bias.
// ---------------------------------------------------------------------------
__global__ __launch_bounds__(256)
void mlp_kernel(const f16* __restrict__ Pg, const float* __restrict__ bgU,
                const float* __restrict__ bc, const float* __restrict__ Wm,
                const float* __restrict__ bmlp, float* __restrict__ out)
{
    int b = blockIdx.z, oc0 = blockIdx.y*32;
    int pix = blockIdx.x*256 + threadIdx.x;
    size_t poff = (size_t)pix*CC;
    const f16* U = Pg + ((size_t)(0*(BB*LL) + b))*HW*CC + poff;
    const f16* C = Pg + ((size_t)(1*(BB*LL) + b))*HW*CC + poff;   // FIXED index
    float acc[32];
    #pragma unroll
    for (int oc=0;oc<32;++oc) acc[oc]=0.f;
    for (int c8 = 0; c8 < 16; ++c8) {
        f16x8 u8 = *(const f16x8*)(U + c8*8);
        f16x8 g8 = *(const f16x8*)(C + c8*8);
        float f[8];
        #pragma unroll
        for (int j=0;j<8;++j) {
            float uu = (float)u8[j] + bgU[c8*8 + j];
            float cc = (float)g8[j] + bc[c8*8 + j];
            float sig = 1.f/(1.f + expf(-uu));
            f[j] = sig * tanhf(cc);
        }
        #pragma unroll
        for (int oc=0; oc<32; ++oc) {
            const float* w = Wm + (size_t)(oc0+oc)*CC + c8*8;
            #pragma unroll
            for (int j=0;j<8;++j) acc[oc] = fmaf(f[j], w[j], acc[oc]);
        }
    }
    #pragma unroll
    for (int oc=0;oc<32;++oc)
        out[((size_t)b*CC + oc0+oc)*HW + pix] = acc[oc] + bmlp[oc0+oc];
}

// ---------------------------------------------------------------------------
extern "C" void kernel_launch(void* const* d_in, const int* in_sizes, int n_in,
                              void* d_out, int out_size, void* d_ws, size_t ws_size,
                              hipStream_t stream)
{
    const float* x     = (const float*)d_in[0];
    const float* mask  = (const float*)d_in[1];
    const float* T     = (const float*)d_in[2];
    const int*   recl  = (const int*)  d_in[3];
    const float* Wmsg  = (const float*)d_in[4];
    const float* bmsg  = (const float*)d_in[5];
    const float* Wg    = (const float*)d_in[6];
    const float* bg    = (const float*)d_in[7];
    const float* Wc    = (const float*)d_in[8];
    const float* bc    = (const float*)d_in[9];
    const float* Wmlp  = (const float*)d_in[10];
    const float* bmlp  = (const float*)d_in[11];
    float* out = (float*)d_out;

    char* w = (char*)d_ws;
    f16*   xT   = (f16*)w;            w += (size_t)BB*LL*HW*CC*2;      // 17.3 MB
    float* fac  = (float*)w;          w += (size_t)32*HW*4;            // 1.1 MB
    f16*   WmF  = (f16*)w;            w += (size_t)9*128*256*2;
    f16*   WuF  = (f16*)w;            w += (size_t)9*128*256*2;
    f16*   WcF  = (f16*)w;            w += (size_t)9*128*256*2;
    f16*   Pm   = (f16*)w;            w += (size_t)40*HW*CC*2;         // 86.5 MB
    f16*   Pg   = (f16*)w;            w += (size_t)2*BB*LL*HW*CC*2;    // 34.6 MB
    f16*   aggT = (f16*)w;            w += (size_t)BB*LL*HW*CC*2;      // 17.3 MB
    f16*   f1T  = (f16*)w;            w += (size_t)BB*LL*HW*CC*2;      // 17.3 MB

    prep_kernel<<<4776, 256, 0, stream>>>(Wmsg, Wg, Wc, x, T, mask,
                                          WmF, WuF, WcF, xT, fac);

    // ---- iteration 1 ----
    msg_conv_kernel<<<dim3(66, 1, BB*LL*5), 256, 0, stream>>>(
        xT, T, fac, mask, recl, WmF, bmsg, Pm, LL);
    reduce_agg_kernel<<<dim3(33, BB*LL), 256, 0, stream>>>(Pm, mask, aggT, LL);
    gru_conv_kernel<<<dim3(66, 2, BB*LL), 256, 0, stream>>>(
        xT, aggT, mask, WuF, WcF, Pg, LL);
    combine_kernel<<<dim3(33, BB*LL), 256, 0, stream>>>(
        Pg, mask, bg + CC, bc, f1T, LL);

    // ---- iteration 2 (only l1=0 consumed) ----
    msg_conv_kernel<<<dim3(66, 1, BB*5), 256, 0, stream>>>(
        f1T, T, fac, mask, recl, WmF, bmsg, Pm, 1);
    reduce_agg_kernel<<<dim3(33, BB), 256, 0, stream>>>(Pm, mask, aggT, 1);
    gru_conv_kernel<<<dim3(66, 2, BB), 256, 0, stream>>>(
        f1T, aggT, mask, WuF, WcF, Pg, 1);

    // ---- final: combine(iter2) fused into MLP ----
    mlp_kernel<<<dim3(33, 4, BB), 256, 0, stream>>>(
        Pg, bg + CC, bc, Wmlp, bmlp, out);
}

// Round 17
// 460.953 us; speedup vs baseline: 1.2603x; 1.0934x over previous
//
#include <hip/hip_runtime.h>
#include <math.h>

#define BB 2
#define LL 4
#define CC 128
#define HH 48
#define WWID 176
#define HW 8448   // 48*176

typedef _Float16 f16;
typedef __attribute__((ext_vector_type(8))) _Float16 f16x8;
typedef __attribute__((ext_vector_type(4))) _Float16 f16x4;
typedef __attribute__((ext_vector_type(2))) _Float16 f16x2;
typedef __attribute__((ext_vector_type(4))) float f32x4;
typedef __attribute__((ext_vector_type(4))) unsigned int u32x4;

// inverse affine from a 4x4 pairwise T block
__device__ __forceinline__ void ainv_from(const float* __restrict__ t, float* a)
{
    float R00=t[0], R01=t[1], t0=t[3];
    float R10=t[4], R11=t[5], t1=t[7];
    float tx = t0 * 0.625f;              // / (RATIO*DS) = /1.6
    float ty = t1 * 0.625f;
    const float cx = WWID/2.0f, cy = HH/2.0f;
    float ftx = cx - (R00*cx + R01*cy) + tx;
    float fty = cy - (R10*cx + R11*cy) + ty;
    float det = R00*R11 - R01*R10;
    float inv = 1.0f/det;
    float i00 =  R11*inv, i01 = -R01*inv, i10 = -R10*inv, i11 = R00*inv;
    a[0]=i00; a[1]=i01; a[2]=-(i00*ftx + i01*fty);
    a[3]=i10; a[4]=i11; a[5]=-(i10*ftx + i11*fty);
}

// ---------------------------------------------------------------------------
// prep: one dispatch doing weight repack (fragment order), x->f16 transpose,
// and fac maps.  Block-id switch.
// ---------------------------------------------------------------------------
__global__ __launch_bounds__(256)
void prep_kernel(const float* __restrict__ Wm, const float* __restrict__ Wg,
                 const float* __restrict__ Wc, const float* __restrict__ x,
                 const float* __restrict__ T, const float* __restrict__ mask,
                 f16* __restrict__ WmF, f16* __restrict__ WuF, f16* __restrict__ WcF,
                 f16* __restrict__ xT, float* __restrict__ fac)
{
    int bid = blockIdx.x;
    int tid = threadIdx.x;
    if (bid < 3456) {
        int which = bid / 1152;
        const float* src = (which==0) ? Wm : (which==1) ? Wg : Wc;
        f16* dst         = (which==0) ? WmF : (which==1) ? WuF : WcF;
        int oc_off = (which==1) ? 128 : 0;
        int stride = (which==0) ? 256 : 384;
        int idx = (bid % 1152)*256 + tid;
        int j     = idx & 7;
        int hi    = (idx >> 3) & 3;
        int l15   = (idx >> 5) & 15;
        int ocblk = (idx >> 9) & 7;
        int kq    = (idx >> 12) & 7;
        int tap   = idx >> 15;
        int oc  = ocblk*16 + l15;
        int cin = kq*32 + hi*8 + j;
        dst[idx] = (f16)src[((size_t)(oc_off+oc)*stride + cin)*9 + tap];
    } else if (bid < 3720) {
        int g = bid - 3456;
        int bl = g / 33;
        int pix = (g % 33)*256 + tid;
        const float* src = x + (size_t)bl*CC*HW + pix;
        f16* dst = xT + (size_t)bl*HW*CC + (size_t)pix*CC;
        for (int gg = 0; gg < 8; ++gg) {
            f16x8 v0, v1;
            #pragma unroll
            for (int c2 = 0; c2 < 8; ++c2) {
                v0[c2] = (f16)src[(size_t)(gg*16 + c2    )*HW];
                v1[c2] = (f16)src[(size_t)(gg*16 + 8 + c2)*HW];
            }
            *(f16x8*)(dst + gg*16    ) = v0;
            *(f16x8*)(dst + gg*16 + 8) = v1;
        }
    } else {
        int g = bid - 3720;
        int slot = g / 33;                    // (b<<4)|(l2<<2)|l1
        int pix = (g % 33)*256 + tid;
        int b = slot >> 4, l2 = (slot >> 2) & 3;
        float mk = mask[b*LL + l2];
        float a[6];
        ainv_from(T + slot*16, a);
        float gx = (float)(pix % WWID), gy = (float)(pix / WWID);
        float sx = a[0]*gx + a[1]*gy + a[2];
        float sy = a[3]*gx + a[4]*gy + a[5];
        float x0 = floorf(sx), y0 = floorf(sy);
        float wx = sx-x0, wy = sy-y0;
        int xi=(int)x0, yi=(int)y0;
        bool vx0 = xi>=0 && xi<WWID, vx1 = xi+1>=0 && xi+1<WWID;
        bool vy0 = yi>=0 && yi<HH,   vy1 = yi+1>=0 && yi+1<HH;
        float r = (vx0&&vy0?(1.f-wx)*(1.f-wy):0.f) + (vx1&&vy0?wx*(1.f-wy):0.f)
                + (vx0&&vy1?(1.f-wx)*wy:0.f)       + (vx1&&vy1?wx*wy:0.f);
        fac[(size_t)slot*HW + pix] = r*mk;
    }
}

// ===========================================================================
// msg conv, templated on NM = oc-fragments per wave (4 = full block, as
// round 16; 2 = oc-split via blockIdx.y=och for underfilled dispatches).
// One JOB per block-z: z = (b, l1, src).  src<4: sender l2=src (gather
// unless l2==l1), weights cin[0:128), scale fac; src==4: ego, cin[128:256),
// scale facsum, +bias.  4 waves, fragment-order A, pk-f16 blend.
// ===========================================================================
template<int NM>
__global__ __launch_bounds__(256,3)
void msg_conv_kernel(const f16* __restrict__ featT, const float* __restrict__ T,
                     const float* __restrict__ fac, const float* __restrict__ mask,
                     const int* __restrict__ reclen,
                     const f16* __restrict__ WmF, const float* __restrict__ bm,
                     f16* __restrict__ Pm, int n_l1)
{
    int z = blockIdx.z;
    int b = z / (n_l1*5);
    int rem = z - b*(n_l1*5);
    int l1 = rem / 5, src = rem % 5;
    if (l1 != 0 && mask[b*LL + l1] == 0.f) return;   // output never consumed
    bool ego = (src == 4);
    int l2 = ego ? l1 : src;
    if (!ego && mask[b*LL + l2] == 0.f) return;      // sender inactive
    bool gather = (!ego) && (l2 != l1);
    int och = blockIdx.y;                            // 0 when grid.y==1

    int ty = blockIdx.x / 11, tx = blockIdx.x % 11;
    int y0 = ty*8, x0 = tx*16;
    int tid = threadIdx.x;
    int wid = tid >> 6, lane = tid & 63;
    int wr = wid >> 1, wc = wid & 1;
    int l15 = lane & 15, hi = lane >> 4;

    __shared__ short lt[180*128];        // 45 KB
    __shared__ float tw[4][192];
    __shared__ int   tof[4][192];

    const f16* in = featT + (size_t)(b*LL + l2)*HW*CC;

    if (gather) {
        float a6[6];
        ainv_from(T + ((b*LL + l2)*LL + l1)*16, a6);
        float a0=a6[0],a1=a6[1],a2=a6[2],a3=a6[3],a4=a6[4],a5=a6[5];
        for (int r = tid; r < 180; r += 256) {
            int yy = r / 18, xx = r - yy*18;
            int gy = y0 - 1 + yy, gx = x0 - 1 + xx;
            float w00=0.f,w10=0.f,w01=0.f,w11=0.f;
            int o00=0,o10=0,o01=0,o11=0;
            if (gy>=0 && gy<HH && gx>=0 && gx<WWID) {
                float sx = a0*(float)gx + a1*(float)gy + a2;
                float sy = a3*(float)gx + a4*(float)gy + a5;
                float xf = floorf(sx), yf = floorf(sy);
                float wx = sx-xf, wyv = sy-yf;
                int xi=(int)xf, yi=(int)yf;
                bool vx0=xi>=0&&xi<WWID, vx1=xi+1>=0&&xi+1<WWID;
                bool vy0=yi>=0&&yi<HH,   vy1=yi+1>=0&&yi+1<HH;
                int xc0=min(max(xi,0),WWID-1), xc1=min(max(xi+1,0),WWID-1);
                int yc0=min(max(yi,0),HH-1),   yc1=min(max(yi+1,0),HH-1);
                o00=(yc0*WWID+xc0)*CC; o10=(yc0*WWID+xc1)*CC;
                o01=(yc1*WWID+xc0)*CC; o11=(yc1*WWID+xc1)*CC;
                w00=(vx0&&vy0)?(1.f-wx)*(1.f-wyv):0.f;
                w10=(vx1&&vy0)?wx*(1.f-wyv):0.f;
                w01=(vx0&&vy1)?(1.f-wx)*wyv:0.f;
                w11=(vx1&&vy1)?wx*wyv:0.f;
            }
            tw[0][r]=w00; tw[1][r]=w10; tw[2][r]=w01; tw[3][r]=w11;
            tof[0][r]=o00; tof[1][r]=o10; tof[2][r]=o01; tof[3][r]=o11;
        }
        __syncthreads();
        for (int i = tid; i < 180*16; i += 256) {
            int row = i >> 4, cg = i & 15;
            f16 h00=(f16)tw[0][row], h10=(f16)tw[1][row];
            f16 h01=(f16)tw[2][row], h11=(f16)tw[3][row];
            f16x2 W00={h00,h00}, W10={h10,h10}, W01={h01,h01}, W11={h11,h11};
            int o00=tof[0][row], o10=tof[1][row], o01=tof[2][row], o11=tof[3][row];
            f16x8 t00 = *(const f16x8*)(in + o00 + cg*8);
            f16x8 t10 = *(const f16x8*)(in + o10 + cg*8);
            f16x8 t01 = *(const f16x8*)(in + o01 + cg*8);
            f16x8 t11 = *(const f16x8*)(in + o11 + cg*8);
            const f16x2* p00 = (const f16x2*)&t00;
            const f16x2* p10 = (const f16x2*)&t10;
            const f16x2* p01 = (const f16x2*)&t01;
            const f16x2* p11 = (const f16x2*)&t11;
            f16x8 outv;
            f16x2* po = (f16x2*)&outv;
            #pragma unroll
            for (int q=0;q<4;++q)
                po[q] = p00[q]*W00 + p10[q]*W10 + p01[q]*W01 + p11[q]*W11;
            int byte = row*256 + ((cg*16) ^ ((row&7)<<4));
            *(f16x8*)((char*)lt + byte) = outv;
        }
    } else {
        for (int i = tid; i < 180*16; i += 256) {
            int row = i >> 4, cg = i & 15;
            int yy = row / 18, xx = row - yy*18;
            int gy = y0 - 1 + yy, gx = x0 - 1 + xx;
            u32x4 val = {0,0,0,0};
            if (gy>=0 && gy<HH && gx>=0 && gx<WWID)
                val = *(const u32x4*)(in + (size_t)(gy*WWID+gx)*CC + cg*8);
            int byte = row*256 + ((cg*16) ^ ((row&7)<<4));
            *(u32x4*)((char*)lt + byte) = val;
        }
    }
    __syncthreads();

    f32x4 acc[NM][4];
    #pragma unroll
    for (int m=0;m<NM;++m)
        #pragma unroll
        for (int n=0;n<4;++n) acc[m][n] = (f32x4){0.f,0.f,0.f,0.f};

    const int kqbase = ego ? 4 : 0;
    const f16* wlane = WmF + l15*32 + hi*8;
    __builtin_amdgcn_s_setprio(1);
    for (int tap=0; tap<9; ++tap) {
        int dy = tap/3, dx = tap - dy*3;
        #pragma unroll
        for (int kk=0; kk<4; ++kk) {
            const f16* wt = wlane + (size_t)(((tap*8 + kqbase + kk)*8 + och*4 + wr*NM))*512;
            f16x8 av[NM];
            #pragma unroll
            for (int m=0;m<NM;++m)
                av[m] = *(const f16x8*)(wt + m*512);
            f16x8 bv[4];
            #pragma unroll
            for (int n=0;n<4;++n) {
                int pos = (wc*4 + n + dy)*18 + dx + l15;
                int byte = pos*256 + ((kk*64 + hi*16) ^ ((pos&7)<<4));
                bv[n] = *(const f16x8*)((const char*)lt + byte);
            }
            #pragma unroll
            for (int m=0;m<NM;++m)
                #pragma unroll
                for (int n=0;n<4;++n)
                    acc[m][n] = __builtin_amdgcn_mfma_f32_16x16x32_f16(
                        av[m], bv[n], acc[m][n], 0, 0, 0);
        }
    }
    __builtin_amdgcn_s_setprio(0);

    // per-pixel scale: fac (pair) or facsum (ego), times invrec (precision)
    float invrec = 1.0f / (float)reclen[b];
    float fsc[4];
    if (ego) {
        #pragma unroll
        for (int n=0;n<4;++n) fsc[n] = 0.f;
        for (int j=0;j<LL;++j) {
            if (mask[b*LL + j] == 0.f) continue;
            const float* fp = fac + (size_t)(b*16 + j*4 + l1)*HW;
            #pragma unroll
            for (int n=0;n<4;++n)
                fsc[n] += fp[(y0 + wc*4 + n)*WWID + x0 + l15];
        }
    } else {
        const float* fp = fac + (size_t)(b*16 + l2*4 + l1)*HW;
        #pragma unroll
        for (int n=0;n<4;++n)
            fsc[n] = fp[(y0 + wc*4 + n)*WWID + x0 + l15];
    }
    #pragma unroll
    for (int n=0;n<4;++n) fsc[n] *= invrec;

    f16* outp = Pm + (size_t)z*HW*CC;
    #pragma unroll
    for (int m=0;m<NM;++m) {
        int oc = (och*4 + wr*NM + m)*16 + hi*4;
        f32x4 b4 = {0.f,0.f,0.f,0.f};
        if (ego) b4 = *(const f32x4*)(bm + oc);
        #pragma unroll
        for (int n=0;n<4;++n) {
            int pix = (y0 + wc*4 + n)*WWID + x0 + l15;
            f32x4 v = (acc[m][n] + b4) * fsc[n];
            f16x4 h = {(f16)v[0], (f16)v[1], (f16)v[2], (f16)v[3]};
            *(f16x4*)(outp + (size_t)pix*CC + oc) = h;
        }
    }
}

// ---------------------------------------------------------------------------
// reduce: aggT[zi][pix][c] f16 = sum of active job slabs (invrec pre-folded)
// grid.x = 132; thread handles 32 channels of one pixel (fully coalesced).
// ---------------------------------------------------------------------------
__global__ __launch_bounds__(256)
void reduce_agg_kernel(const f16* __restrict__ Pm, const float* __restrict__ mask,
                       f16* __restrict__ aggT, int n_l1)
{
    int zi = blockIdx.y;                 // b*n_l1 + l1
    int b = zi / n_l1, l1 = zi % n_l1;
    if (l1 != 0 && mask[b*LL + l1] == 0.f) return;
    int idx = blockIdx.x*256 + threadIdx.x;   // 132*256 = 8448*4
    int pix = idx >> 2, cgq = idx & 3;
    bool act[4];
    #pragma unroll
    for (int j=0;j<LL;++j) act[j] = (mask[b*LL + j] != 0.f);
    size_t off = (size_t)pix*CC + cgq*32;
    const f16* base = Pm + (size_t)(zi*5)*HW*CC + off;
    f16* dst = aggT + (size_t)zi*HW*CC + off;
    for (int cg=0; cg<4; ++cg) {
        float s[8];
        f16x8 e = *(const f16x8*)(base + (size_t)4*HW*CC + cg*8);
        #pragma unroll
        for (int j8=0;j8<8;++j8) s[j8] = (float)e[j8];
        #pragma unroll
        for (int j=0;j<4;++j) {
            if (!act[j]) continue;
            f16x8 p = *(const f16x8*)(base + (size_t)j*HW*CC + cg*8);
            #pragma unroll
            for (int j8=0;j8<8;++j8) s[j8] += (float)p[j8];
        }
        f16x8 o;
        #pragma unroll
        for (int j8=0;j8<8;++j8) o[j8] = (f16)s[j8];
        *(f16x8*)(dst + cg*8) = o;
    }
}

// ===========================================================================
// gru conv templated on NM (4 = round-16 structure, 2 = oc-split).
// blockIdx.y = gate*noc + och.  Full K=256 per block (stage feat; MFMA;
// stage agg; MFMA), fragment-order A.  Raw conv -> f16 slab Pg[gate][z].
// ===========================================================================
template<int NM>
__global__ __launch_bounds__(256,3)
void gru_conv_kernel(const f16* __restrict__ featT, const f16* __restrict__ aggT,
                     const float* __restrict__ mask,
                     const f16* __restrict__ WuF, const f16* __restrict__ WcF,
                     f16* __restrict__ Pg, int n_l1, int noc)
{
    int z = blockIdx.z;
    int b = z / n_l1, l1 = z % n_l1;
    if (l1 != 0 && mask[b*LL + l1] == 0.f) return;
    int gate = blockIdx.y / noc;
    int och  = blockIdx.y % noc;

    int ty = blockIdx.x / 11, tx = blockIdx.x % 11;
    int y0 = ty*8, x0 = tx*16;
    int tid = threadIdx.x;
    int wid = tid >> 6, lane = tid & 63;
    int wr = wid >> 1, wc = wid & 1;
    int l15 = lane & 15, hi = lane >> 4;

    __shared__ short lt[180*128];  // 45 KB

    f32x4 acc[NM][4];
    #pragma unroll
    for (int m=0;m<NM;++m)
        #pragma unroll
        for (int n=0;n<4;++n) acc[m][n] = (f32x4){0.f,0.f,0.f,0.f};

    const f16* WF = (gate==0) ? WuF : WcF;
    const f16* wlane = WF + l15*32 + hi*8;

    for (int s = 0; s < 2; ++s) {
        const f16* in = (s==0) ? featT + (size_t)(b*LL + l1)*HW*CC
                               : aggT  + (size_t)(b*n_l1 + l1)*HW*CC;
        if (s) __syncthreads();           // MFMA readers of stage-0 done
        for (int i = tid; i < 180*16; i += 256) {
            int row = i >> 4, cg = i & 15;
            int yy = row / 18, xx = row - yy*18;
            int gy = y0 - 1 + yy, gx = x0 - 1 + xx;
            u32x4 val = {0,0,0,0};
            if (gy>=0 && gy<HH && gx>=0 && gx<WWID)
                val = *(const u32x4*)(in + (size_t)(gy*WWID+gx)*CC + cg*8);
            int byte = row*256 + ((cg*16) ^ ((row&7)<<4));
            *(u32x4*)((char*)lt + byte) = val;
        }
        __syncthreads();

        int kqbase = s*4;
        __builtin_amdgcn_s_setprio(1);
        for (int tap=0; tap<9; ++tap) {
            int dy = tap/3, dx = tap - dy*3;
            #pragma unroll
            for (int kk=0; kk<4; ++kk) {
                const f16* wt = wlane + (size_t)(((tap*8 + kqbase + kk)*8 + och*4 + wr*NM))*512;
                f16x8 av[NM];
                #pragma unroll
                for (int m=0;m<NM;++m)
                    av[m] = *(const f16x8*)(wt + m*512);
                f16x8 bv[4];
                #pragma unroll
                for (int n=0;n<4;++n) {
                    int pos = (wc*4 + n + dy)*18 + dx + l15;
                    int byte = pos*256 + ((kk*64 + hi*16) ^ ((pos&7)<<4));
                    bv[n] = *(const f16x8*)((const char*)lt + byte);
                }
                #pragma unroll
                for (int m=0;m<NM;++m)
                    #pragma unroll
                    for (int n=0;n<4;++n)
                        acc[m][n] = __builtin_amdgcn_mfma_f32_16x16x32_f16(
                            av[m], bv[n], acc[m][n], 0, 0, 0);
            }
        }
        __builtin_amdgcn_s_setprio(0);
    }

    f16* outp = Pg + ((size_t)(gate*(BB*LL) + z))*HW*CC;
    #pragma unroll
    for (int m=0;m<NM;++m) {
        int oc = (och*4 + wr*NM + m)*16 + hi*4;
        #pragma unroll
        for (int n=0;n<4;++n) {
            int pix = (y0 + wc*4 + n)*WWID + x0 + l15;
            f32x4 v = acc[m][n];
            f16x4 h = {(f16)v[0], (f16)v[1], (f16)v[2], (f16)v[3]};
            *(f16x4*)(outp + (size_t)pix*CC + oc) = h;
        }
    }
}

// ---------------------------------------------------------------------------
// combine: h = sigmoid(U+bgU) * tanh(C+bc) -> f16 [z][pix][ch]  (iter 1)
// grid.x = 132; thread handles 32 channels of one pixel.
// ---------------------------------------------------------------------------
__global__ __launch_bounds__(256)
void combine_kernel(const f16* __restrict__ Pg, const float* __restrict__ mask,
                    const float* __restrict__ bgU, const float* __restrict__ bc,
                    f16* __restrict__ outT, int n_l1)
{
    int z = blockIdx.y;
    int b = z / n_l1, l1 = z % n_l1;
    if (l1 != 0 && mask[b*LL + l1] == 0.f) return;
    int idx = blockIdx.x*256 + threadIdx.x;
    int pix = idx >> 2, cgq = idx & 3;
    size_t poff = (size_t)pix*CC + cgq*32;
    const f16* U = Pg + ((size_t)(0*(BB*LL) + z))*HW*CC + poff;
    const f16* C = Pg + ((size_t)(1*(BB*LL) + z))*HW*CC + poff;
    f16* dst = outT + (size_t)z*HW*CC + poff;
    for (int cg=0; cg<4; ++cg) {
        f16x8 u8 = *(const f16x8*)(U + cg*8);
        f16x8 c8 = *(const f16x8*)(C + cg*8);
        f16x8 o;
        #pragma unroll
        for (int j=0; j<8; ++j) {
            float uu = (float)u8[j] + bgU[cgq*32 + cg*8 + j];
            float cc = (float)c8[j] + bc[cgq*32 + cg*8 + j];
            float sig = 1.f/(1.f + expf(-uu));
            o[j] = (f16)(sig * tanhf(cc));
        }
        *(f16x8*)(dst + cg*8) = o;
    }
}

// ---------------------------------------------------------------------------
// mlp+combine (iter 2): h = sigmoid(U+bgU)*tanh(C+bc) inline from gate slabs
// (z = b; C slab at BB*LL + b), then out[b][oc][pix] = W h + bias.
// ---------------------------------------------------------------------------
__global__ __launch_bounds__(256)
void mlp_kernel(const f16* __restrict__ Pg, const float* __restrict__ bgU,
                const float* __restrict__ bc, const float* __restrict__ Wm,
                const float* __restrict__ bmlp, float* __restrict__ out)
{
    int b = blockIdx.z, oc0 = blockIdx.y*32;
    int pix = blockIdx.x*256 + threadIdx.x;
    size_t poff = (size_t)pix*CC;
    const f16* U = Pg + ((size_t)(0*(BB*LL) + b))*HW*CC + poff;
    const f16* C = Pg + ((size_t)(1*(BB*LL) + b))*HW*CC + poff;
    float acc[32];
    #pragma unroll
    for (int oc=0;oc<32;++oc) acc[oc]=0.f;
    for (int c8 = 0; c8 < 16; ++c8) {
        f16x8 u8 = *(const f16x8*)(U + c8*8);
        f16x8 g8 = *(const f16x8*)(C + c8*8);
        float f[8];
        #pragma unroll
        for (int j=0;j<8;++j) {
            float uu = (float)u8[j] + bgU[c8*8 + j];
            float cc = (float)g8[j] + bc[c8*8 + j];
            float sig = 1.f/(1.f + expf(-uu));
            f[j] = sig * tanhf(cc);
        }
        #pragma unroll
        for (int oc=0; oc<32; ++oc) {
            const float* w = Wm + (size_t)(oc0+oc)*CC + c8*8;
            #pragma unroll
            for (int j=0;j<8;++j) acc[oc] = fmaf(f[j], w[j], acc[oc]);
        }
    }
    #pragma unroll
    for (int oc=0;oc<32;++oc)
        out[((size_t)b*CC + oc0+oc)*HW + pix] = acc[oc] + bmlp[oc0+oc];
}

// ---------------------------------------------------------------------------
extern "C" void kernel_launch(void* const* d_in, const int* in_sizes, int n_in,
                              void* d_out, int out_size, void* d_ws, size_t ws_size,
                              hipStream_t stream)
{
    const float* x     = (const float*)d_in[0];
    const float* mask  = (const float*)d_in[1];
    const float* T     = (const float*)d_in[2];
    const int*   recl  = (const int*)  d_in[3];
    const float* Wmsg  = (const float*)d_in[4];
    const float* bmsg  = (const float*)d_in[5];
    const float* Wg    = (const float*)d_in[6];
    const float* bg    = (const float*)d_in[7];
    const float* Wc    = (const float*)d_in[8];
    const float* bc    = (const float*)d_in[9];
    const float* Wmlp  = (const float*)d_in[10];
    const float* bmlp  = (const float*)d_in[11];
    float* out = (float*)d_out;

    char* w = (char*)d_ws;
    f16*   xT   = (f16*)w;            w += (size_t)BB*LL*HW*CC*2;      // 17.3 MB
    float* fac  = (float*)w;          w += (size_t)32*HW*4;            // 1.1 MB
    f16*   WmF  = (f16*)w;            w += (size_t)9*128*256*2;
    f16*   WuF  = (f16*)w;            w += (size_t)9*128*256*2;
    f16*   WcF  = (f16*)w;            w += (size_t)9*128*256*2;
    f16*   Pm   = (f16*)w;            w += (size_t)40*HW*CC*2;         // 86.5 MB
    f16*   Pg   = (f16*)w;            w += (size_t)2*BB*LL*HW*CC*2;    // 34.6 MB
    f16*   aggT = (f16*)w;            w += (size_t)BB*LL*HW*CC*2;      // 17.3 MB
    f16*   f1T  = (f16*)w;            w += (size_t)BB*LL*HW*CC*2;      // 17.3 MB

    prep_kernel<<<4776, 256, 0, stream>>>(Wmsg, Wg, Wc, x, T, mask,
                                          WmF, WuF, WcF, xT, fac);

    // ---- iteration 1 (NM=4, identical to round-16 kernels) ----
    msg_conv_kernel<4><<<dim3(66, 1, BB*LL*5), 256, 0, stream>>>(
        xT, T, fac, mask, recl, WmF, bmsg, Pm, LL);
    reduce_agg_kernel<<<dim3(132, BB*LL), 256, 0, stream>>>(Pm, mask, aggT, LL);
    gru_conv_kernel<4><<<dim3(66, 2, BB*LL), 256, 0, stream>>>(
        xT, aggT, mask, WuF, WcF, Pg, LL, 1);
    combine_kernel<<<dim3(132, BB*LL), 256, 0, stream>>>(
        Pg, mask, bg + CC, bc, f1T, LL);

    // ---- iteration 2 (NM=2 oc-split: double the block count) ----
    msg_conv_kernel<2><<<dim3(66, 2, BB*5), 256, 0, stream>>>(
        f1T, T, fac, mask, recl, WmF, bmsg, Pm, 1);
    reduce_agg_kernel<<<dim3(132, BB), 256, 0, stream>>>(Pm, mask, aggT, 1);
    gru_conv_kernel<2><<<dim3(66, 4, BB), 256, 0, stream>>>(
        f1T, aggT, mask, WuF, WcF, Pg, 1, 2);

    // ---- final: combine(iter2) fused into MLP ----
    mlp_kernel<<<dim3(33, 4, BB), 256, 0, stream>>>(
        Pg, bg + CC, bc, Wmlp, bmlp, out);
}

// Round 18
// 459.543 us; speedup vs baseline: 1.2642x; 1.0031x over previous
//
#include <hip/hip_runtime.h>
#include <math.h>

#define BB 2
#define LL 4
#define CC 128
#define HH 48
#define WWID 176
#define HW 8448   // 48*176

typedef _Float16 f16;
typedef __attribute__((ext_vector_type(8))) _Float16 f16x8;
typedef __attribute__((ext_vector_type(4))) _Float16 f16x4;
typedef __attribute__((ext_vector_type(2))) _Float16 f16x2;
typedef __attribute__((ext_vector_type(4))) float f32x4;
typedef __attribute__((ext_vector_type(4))) unsigned int u32x4;

// inverse affine from a 4x4 pairwise T block
__device__ __forceinline__ void ainv_from(const float* __restrict__ t, float* a)
{
    float R00=t[0], R01=t[1], t0=t[3];
    float R10=t[4], R11=t[5], t1=t[7];
    float tx = t0 * 0.625f;              // / (RATIO*DS) = /1.6
    float ty = t1 * 0.625f;
    const float cx = WWID/2.0f, cy = HH/2.0f;
    float ftx = cx - (R00*cx + R01*cy) + tx;
    float fty = cy - (R10*cx + R11*cy) + ty;
    float det = R00*R11 - R01*R10;
    float inv = 1.0f/det;
    float i00 =  R11*inv, i01 = -R01*inv, i10 = -R10*inv, i11 = R00*inv;
    a[0]=i00; a[1]=i01; a[2]=-(i00*ftx + i01*fty);
    a[3]=i10; a[4]=i11; a[5]=-(i10*ftx + i11*fty);
}

// ---------------------------------------------------------------------------
// prep: one dispatch doing weight repack (fragment order), x->f16 transpose,
// and fac maps.  Block-id switch.
// ---------------------------------------------------------------------------
__global__ __launch_bounds__(256)
void prep_kernel(const float* __restrict__ Wm, const float* __restrict__ Wg,
                 const float* __restrict__ Wc, const float* __restrict__ x,
                 const float* __restrict__ T, const float* __restrict__ mask,
                 f16* __restrict__ WmF, f16* __restrict__ WuF, f16* __restrict__ WcF,
                 f16* __restrict__ xT, float* __restrict__ fac)
{
    int bid = blockIdx.x;
    int tid = threadIdx.x;
    if (bid < 3456) {
        int which = bid / 1152;
        const float* src = (which==0) ? Wm : (which==1) ? Wg : Wc;
        f16* dst         = (which==0) ? WmF : (which==1) ? WuF : WcF;
        int oc_off = (which==1) ? 128 : 0;
        int stride = (which==0) ? 256 : 384;
        int idx = (bid % 1152)*256 + tid;
        int j     = idx & 7;
        int hi    = (idx >> 3) & 3;
        int l15   = (idx >> 5) & 15;
        int ocblk = (idx >> 9) & 7;
        int kq    = (idx >> 12) & 7;
        int tap   = idx >> 15;
        int oc  = ocblk*16 + l15;
        int cin = kq*32 + hi*8 + j;
        dst[idx] = (f16)src[((size_t)(oc_off+oc)*stride + cin)*9 + tap];
    } else if (bid < 3720) {
        int g = bid - 3456;
        int bl = g / 33;
        int pix = (g % 33)*256 + tid;
        const float* src = x + (size_t)bl*CC*HW + pix;
        f16* dst = xT + (size_t)bl*HW*CC + (size_t)pix*CC;
        for (int gg = 0; gg < 8; ++gg) {
            f16x8 v0, v1;
            #pragma unroll
            for (int c2 = 0; c2 < 8; ++c2) {
                v0[c2] = (f16)src[(size_t)(gg*16 + c2    )*HW];
                v1[c2] = (f16)src[(size_t)(gg*16 + 8 + c2)*HW];
            }
            *(f16x8*)(dst + gg*16    ) = v0;
            *(f16x8*)(dst + gg*16 + 8) = v1;
        }
    } else {
        int g = bid - 3720;
        int slot = g / 33;                    // (b<<4)|(l2<<2)|l1
        int pix = (g % 33)*256 + tid;
        int b = slot >> 4, l2 = (slot >> 2) & 3;
        float mk = mask[b*LL + l2];
        float a[6];
        ainv_from(T + slot*16, a);
        float gx = (float)(pix % WWID), gy = (float)(pix / WWID);
        float sx = a[0]*gx + a[1]*gy + a[2];
        float sy = a[3]*gx + a[4]*gy + a[5];
        float x0 = floorf(sx), y0 = floorf(sy);
        float wx = sx-x0, wy = sy-y0;
        int xi=(int)x0, yi=(int)y0;
        bool vx0 = xi>=0 && xi<WWID, vx1 = xi+1>=0 && xi+1<WWID;
        bool vy0 = yi>=0 && yi<HH,   vy1 = yi+1>=0 && yi+1<HH;
        float r = (vx0&&vy0?(1.f-wx)*(1.f-wy):0.f) + (vx1&&vy0?wx*(1.f-wy):0.f)
                + (vx0&&vy1?(1.f-wx)*wy:0.f)       + (vx1&&vy1?wx*wy:0.f);
        fac[(size_t)slot*HW + pix] = r*mk;
    }
}

// ===========================================================================
// msg conv, templated on NM (4 = full block; 2 = oc-split via blockIdx.y).
// One JOB per block-z: z = (b, l1, src).  (round-17, proven)
// ===========================================================================
template<int NM>
__global__ __launch_bounds__(256,3)
void msg_conv_kernel(const f16* __restrict__ featT, const float* __restrict__ T,
                     const float* __restrict__ fac, const float* __restrict__ mask,
                     const int* __restrict__ reclen,
                     const f16* __restrict__ WmF, const float* __restrict__ bm,
                     f16* __restrict__ Pm, int n_l1)
{
    int z = blockIdx.z;
    int b = z / (n_l1*5);
    int rem = z - b*(n_l1*5);
    int l1 = rem / 5, src = rem % 5;
    if (l1 != 0 && mask[b*LL + l1] == 0.f) return;   // output never consumed
    bool ego = (src == 4);
    int l2 = ego ? l1 : src;
    if (!ego && mask[b*LL + l2] == 0.f) return;      // sender inactive
    bool gather = (!ego) && (l2 != l1);
    int och = blockIdx.y;                            // 0 when grid.y==1

    int ty = blockIdx.x / 11, tx = blockIdx.x % 11;
    int y0 = ty*8, x0 = tx*16;
    int tid = threadIdx.x;
    int wid = tid >> 6, lane = tid & 63;
    int wr = wid >> 1, wc = wid & 1;
    int l15 = lane & 15, hi = lane >> 4;

    __shared__ short lt[180*128];        // 45 KB
    __shared__ float tw[4][192];
    __shared__ int   tof[4][192];

    const f16* in = featT + (size_t)(b*LL + l2)*HW*CC;

    if (gather) {
        float a6[6];
        ainv_from(T + ((b*LL + l2)*LL + l1)*16, a6);
        float a0=a6[0],a1=a6[1],a2=a6[2],a3=a6[3],a4=a6[4],a5=a6[5];
        for (int r = tid; r < 180; r += 256) {
            int yy = r / 18, xx = r - yy*18;
            int gy = y0 - 1 + yy, gx = x0 - 1 + xx;
            float w00=0.f,w10=0.f,w01=0.f,w11=0.f;
            int o00=0,o10=0,o01=0,o11=0;
            if (gy>=0 && gy<HH && gx>=0 && gx<WWID) {
                float sx = a0*(float)gx + a1*(float)gy + a2;
                float sy = a3*(float)gx + a4*(float)gy + a5;
                float xf = floorf(sx), yf = floorf(sy);
                float wx = sx-xf, wyv = sy-yf;
                int xi=(int)xf, yi=(int)yf;
                bool vx0=xi>=0&&xi<WWID, vx1=xi+1>=0&&xi+1<WWID;
                bool vy0=yi>=0&&yi<HH,   vy1=yi+1>=0&&yi+1<HH;
                int xc0=min(max(xi,0),WWID-1), xc1=min(max(xi+1,0),WWID-1);
                int yc0=min(max(yi,0),HH-1),   yc1=min(max(yi+1,0),HH-1);
                o00=(yc0*WWID+xc0)*CC; o10=(yc0*WWID+xc1)*CC;
                o01=(yc1*WWID+xc0)*CC; o11=(yc1*WWID+xc1)*CC;
                w00=(vx0&&vy0)?(1.f-wx)*(1.f-wyv):0.f;
                w10=(vx1&&vy0)?wx*(1.f-wyv):0.f;
                w01=(vx0&&vy1)?(1.f-wx)*wyv:0.f;
                w11=(vx1&&vy1)?wx*wyv:0.f;
            }
            tw[0][r]=w00; tw[1][r]=w10; tw[2][r]=w01; tw[3][r]=w11;
            tof[0][r]=o00; tof[1][r]=o10; tof[2][r]=o01; tof[3][r]=o11;
        }
        __syncthreads();
        for (int i = tid; i < 180*16; i += 256) {
            int row = i >> 4, cg = i & 15;
            f16 h00=(f16)tw[0][row], h10=(f16)tw[1][row];
            f16 h01=(f16)tw[2][row], h11=(f16)tw[3][row];
            f16x2 W00={h00,h00}, W10={h10,h10}, W01={h01,h01}, W11={h11,h11};
            int o00=tof[0][row], o10=tof[1][row], o01=tof[2][row], o11=tof[3][row];
            f16x8 t00 = *(const f16x8*)(in + o00 + cg*8);
            f16x8 t10 = *(const f16x8*)(in + o10 + cg*8);
            f16x8 t01 = *(const f16x8*)(in + o01 + cg*8);
            f16x8 t11 = *(const f16x8*)(in + o11 + cg*8);
            const f16x2* p00 = (const f16x2*)&t00;
            const f16x2* p10 = (const f16x2*)&t10;
            const f16x2* p01 = (const f16x2*)&t01;
            const f16x2* p11 = (const f16x2*)&t11;
            f16x8 outv;
            f16x2* po = (f16x2*)&outv;
            #pragma unroll
            for (int q=0;q<4;++q)
                po[q] = p00[q]*W00 + p10[q]*W10 + p01[q]*W01 + p11[q]*W11;
            int byte = row*256 + ((cg*16) ^ ((row&7)<<4));
            *(f16x8*)((char*)lt + byte) = outv;
        }
    } else {
        for (int i = tid; i < 180*16; i += 256) {
            int row = i >> 4, cg = i & 15;
            int yy = row / 18, xx = row - yy*18;
            int gy = y0 - 1 + yy, gx = x0 - 1 + xx;
            u32x4 val = {0,0,0,0};
            if (gy>=0 && gy<HH && gx>=0 && gx<WWID)
                val = *(const u32x4*)(in + (size_t)(gy*WWID+gx)*CC + cg*8);
            int byte = row*256 + ((cg*16) ^ ((row&7)<<4));
            *(u32x4*)((char*)lt + byte) = val;
        }
    }
    __syncthreads();

    f32x4 acc[NM][4];
    #pragma unroll
    for (int m=0;m<NM;++m)
        #pragma unroll
        for (int n=0;n<4;++n) acc[m][n] = (f32x4){0.f,0.f,0.f,0.f};

    const int kqbase = ego ? 4 : 0;
    const f16* wlane = WmF + l15*32 + hi*8;
    __builtin_amdgcn_s_setprio(1);
    for (int tap=0; tap<9; ++tap) {
        int dy = tap/3, dx = tap - dy*3;
        #pragma unroll
        for (int kk=0; kk<4; ++kk) {
            const f16* wt = wlane + (size_t)(((tap*8 + kqbase + kk)*8 + och*4 + wr*NM))*512;
            f16x8 av[NM];
            #pragma unroll
            for (int m=0;m<NM;++m)
                av[m] = *(const f16x8*)(wt + m*512);
            f16x8 bv[4];
            #pragma unroll
            for (int n=0;n<4;++n) {
                int pos = (wc*4 + n + dy)*18 + dx + l15;
                int byte = pos*256 + ((kk*64 + hi*16) ^ ((pos&7)<<4));
                bv[n] = *(const f16x8*)((const char*)lt + byte);
            }
            #pragma unroll
            for (int m=0;m<NM;++m)
                #pragma unroll
                for (int n=0;n<4;++n)
                    acc[m][n] = __builtin_amdgcn_mfma_f32_16x16x32_f16(
                        av[m], bv[n], acc[m][n], 0, 0, 0);
        }
    }
    __builtin_amdgcn_s_setprio(0);

    // per-pixel scale: fac (pair) or facsum (ego), times invrec (precision)
    float invrec = 1.0f / (float)reclen[b];
    float fsc[4];
    if (ego) {
        #pragma unroll
        for (int n=0;n<4;++n) fsc[n] = 0.f;
        for (int j=0;j<LL;++j) {
            if (mask[b*LL + j] == 0.f) continue;
            const float* fp = fac + (size_t)(b*16 + j*4 + l1)*HW;
            #pragma unroll
            for (int n=0;n<4;++n)
                fsc[n] += fp[(y0 + wc*4 + n)*WWID + x0 + l15];
        }
    } else {
        const float* fp = fac + (size_t)(b*16 + l2*4 + l1)*HW;
        #pragma unroll
        for (int n=0;n<4;++n)
            fsc[n] = fp[(y0 + wc*4 + n)*WWID + x0 + l15];
    }
    #pragma unroll
    for (int n=0;n<4;++n) fsc[n] *= invrec;

    f16* outp = Pm + (size_t)z*HW*CC;
    #pragma unroll
    for (int m=0;m<NM;++m) {
        int oc = (och*4 + wr*NM + m)*16 + hi*4;
        f32x4 b4 = {0.f,0.f,0.f,0.f};
        if (ego) b4 = *(const f32x4*)(bm + oc);
        #pragma unroll
        for (int n=0;n<4;++n) {
            int pix = (y0 + wc*4 + n)*WWID + x0 + l15;
            f32x4 v = (acc[m][n] + b4) * fsc[n];
            f16x4 h = {(f16)v[0], (f16)v[1], (f16)v[2], (f16)v[3]};
            *(f16x4*)(outp + (size_t)pix*CC + oc) = h;
        }
    }
}

// ---------------------------------------------------------------------------
// reduce: aggT[zi][pix][c] f16 = sum of active job slabs (invrec pre-folded)
// grid.x = 132; thread handles 32 channels of one pixel (fully coalesced).
// ---------------------------------------------------------------------------
__global__ __launch_bounds__(256)
void reduce_agg_kernel(const f16* __restrict__ Pm, const float* __restrict__ mask,
                       f16* __restrict__ aggT, int n_l1)
{
    int zi = blockIdx.y;                 // b*n_l1 + l1
    int b = zi / n_l1, l1 = zi % n_l1;
    if (l1 != 0 && mask[b*LL + l1] == 0.f) return;
    int idx = blockIdx.x*256 + threadIdx.x;   // 132*256 = 8448*4
    int pix = idx >> 2, cgq = idx & 3;
    bool act[4];
    #pragma unroll
    for (int j=0;j<LL;++j) act[j] = (mask[b*LL + j] != 0.f);
    size_t off = (size_t)pix*CC + cgq*32;
    const f16* base = Pm + (size_t)(zi*5)*HW*CC + off;
    f16* dst = aggT + (size_t)zi*HW*CC + off;
    for (int cg=0; cg<4; ++cg) {
        float s[8];
        f16x8 e = *(const f16x8*)(base + (size_t)4*HW*CC + cg*8);
        #pragma unroll
        for (int j8=0;j8<8;++j8) s[j8] = (float)e[j8];
        #pragma unroll
        for (int j=0;j<4;++j) {
            if (!act[j]) continue;
            f16x8 p = *(const f16x8*)(base + (size_t)j*HW*CC + cg*8);
            #pragma unroll
            for (int j8=0;j8<8;++j8) s[j8] += (float)p[j8];
        }
        f16x8 o;
        #pragma unroll
        for (int j8=0;j8<8;++j8) o[j8] = (f16)s[j8];
        *(f16x8*)(dst + cg*8) = o;
    }
}

// ===========================================================================
// gru conv templated on NM (4 / 2).  blockIdx.y = gate*noc + och.
// T14 async-stage: agg-tile loads issued to REGISTERS before the s=0 MFMA
// (HBM/L2 latency hides under ~2900cy of MFMA); post-barrier only ds_writes.
// pf covers items [0,2048); remainder staged normally.  Same 3 barriers.
// ===========================================================================
template<int NM>
__global__ __launch_bounds__(256,3)
void gru_conv_kernel(const f16* __restrict__ featT, const f16* __restrict__ aggT,
                     const float* __restrict__ mask,
                     const f16* __restrict__ WuF, const f16* __restrict__ WcF,
                     f16* __restrict__ Pg, int n_l1, int noc)
{
    int z = blockIdx.z;
    int b = z / n_l1, l1 = z % n_l1;
    if (l1 != 0 && mask[b*LL + l1] == 0.f) return;
    int gate = blockIdx.y / noc;
    int och  = blockIdx.y % noc;

    int ty = blockIdx.x / 11, tx = blockIdx.x % 11;
    int y0 = ty*8, x0 = tx*16;
    int tid = threadIdx.x;
    int wid = tid >> 6, lane = tid & 63;
    int wr = wid >> 1, wc = wid & 1;
    int l15 = lane & 15, hi = lane >> 4;

    __shared__ short lt[180*128];  // 45 KB

    f32x4 acc[NM][4];
    #pragma unroll
    for (int m=0;m<NM;++m)
        #pragma unroll
        for (int n=0;n<4;++n) acc[m][n] = (f32x4){0.f,0.f,0.f,0.f};

    const f16* WF = (gate==0) ? WuF : WcF;
    const f16* wlane = WF + l15*32 + hi*8;

    const f16* in0 = featT + (size_t)(b*LL + l1)*HW*CC;
    const f16* in1 = aggT  + (size_t)(b*n_l1 + l1)*HW*CC;

    // ---- stage s=0 (feat) into LDS ----
    for (int i = tid; i < 180*16; i += 256) {
        int row = i >> 4, cg = i & 15;
        int yy = row / 18, xx = row - yy*18;
        int gy = y0 - 1 + yy, gx = x0 - 1 + xx;
        u32x4 val = {0,0,0,0};
        if (gy>=0 && gy<HH && gx>=0 && gx<WWID)
            val = *(const u32x4*)(in0 + (size_t)(gy*WWID+gx)*CC + cg*8);
        int byte = row*256 + ((cg*16) ^ ((row&7)<<4));
        *(u32x4*)((char*)lt + byte) = val;
    }

    // ---- issue agg-tile prefetch (items [0,2048)) into registers ----
    u32x4 pf[8];
    #pragma unroll
    for (int k = 0; k < 8; ++k) {
        int i = tid + k*256;
        int row = i >> 4, cg = i & 15;
        int yy = row / 18, xx = row - yy*18;
        int gy = y0 - 1 + yy, gx = x0 - 1 + xx;
        u32x4 v = {0,0,0,0};
        if (gy>=0 && gy<HH && gx>=0 && gx<WWID)
            v = *(const u32x4*)(in1 + (size_t)(gy*WWID+gx)*CC + cg*8);
        pf[k] = v;
    }
    __syncthreads();

    // ---- MFMA s=0 (kq 0..3) ----
    __builtin_amdgcn_s_setprio(1);
    for (int tap=0; tap<9; ++tap) {
        int dy = tap/3, dx = tap - dy*3;
        #pragma unroll
        for (int kk=0; kk<4; ++kk) {
            const f16* wt = wlane + (size_t)(((tap*8 + kk)*8 + och*4 + wr*NM))*512;
            f16x8 av[NM];
            #pragma unroll
            for (int m=0;m<NM;++m)
                av[m] = *(const f16x8*)(wt + m*512);
            f16x8 bv[4];
            #pragma unroll
            for (int n=0;n<4;++n) {
                int pos = (wc*4 + n + dy)*18 + dx + l15;
                int byte = pos*256 + ((kk*64 + hi*16) ^ ((pos&7)<<4));
                bv[n] = *(const f16x8*)((const char*)lt + byte);
            }
            #pragma unroll
            for (int m=0;m<NM;++m)
                #pragma unroll
                for (int n=0;n<4;++n)
                    acc[m][n] = __builtin_amdgcn_mfma_f32_16x16x32_f16(
                        av[m], bv[n], acc[m][n], 0, 0, 0);
        }
    }
    __builtin_amdgcn_s_setprio(0);
    __syncthreads();     // s=0 LDS readers done

    // ---- write prefetched agg chunks; stage remainder normally ----
    #pragma unroll
    for (int k = 0; k < 8; ++k) {
        int i = tid + k*256;
        int row = i >> 4, cg = i & 15;
        int byte = row*256 + ((cg*16) ^ ((row&7)<<4));
        *(u32x4*)((char*)lt + byte) = pf[k];
    }
    for (int i = 2048 + tid; i < 180*16; i += 256) {
        int row = i >> 4, cg = i & 15;
        int yy = row / 18, xx = row - yy*18;
        int gy = y0 - 1 + yy, gx = x0 - 1 + xx;
        u32x4 val = {0,0,0,0};
        if (gy>=0 && gy<HH && gx>=0 && gx<WWID)
            val = *(const u32x4*)(in1 + (size_t)(gy*WWID+gx)*CC + cg*8);
        int byte = row*256 + ((cg*16) ^ ((row&7)<<4));
        *(u32x4*)((char*)lt + byte) = val;
    }
    __syncthreads();

    // ---- MFMA s=1 (kq 4..7) ----
    __builtin_amdgcn_s_setprio(1);
    for (int tap=0; tap<9; ++tap) {
        int dy = tap/3, dx = tap - dy*3;
        #pragma unroll
        for (int kk=0; kk<4; ++kk) {
            const f16* wt = wlane + (size_t)(((tap*8 + 4 + kk)*8 + och*4 + wr*NM))*512;
            f16x8 av[NM];
            #pragma unroll
            for (int m=0;m<NM;++m)
                av[m] = *(const f16x8*)(wt + m*512);
            f16x8 bv[4];
            #pragma unroll
            for (int n=0;n<4;++n) {
                int pos = (wc*4 + n + dy)*18 + dx + l15;
                int byte = pos*256 + ((kk*64 + hi*16) ^ ((pos&7)<<4));
                bv[n] = *(const f16x8*)((const char*)lt + byte);
            }
            #pragma unroll
            for (int m=0;m<NM;++m)
                #pragma unroll
                for (int n=0;n<4;++n)
                    acc[m][n] = __builtin_amdgcn_mfma_f32_16x16x32_f16(
                        av[m], bv[n], acc[m][n], 0, 0, 0);
        }
    }
    __builtin_amdgcn_s_setprio(0);

    f16* outp = Pg + ((size_t)(gate*(BB*LL) + z))*HW*CC;
    #pragma unroll
    for (int m=0;m<NM;++m) {
        int oc = (och*4 + wr*NM + m)*16 + hi*4;
        #pragma unroll
        for (int n=0;n<4;++n) {
            int pix = (y0 + wc*4 + n)*WWID + x0 + l15;
            f32x4 v = acc[m][n];
            f16x4 h = {(f16)v[0], (f16)v[1], (f16)v[2], (f16)v[3]};
            *(f16x4*)(outp + (size_t)pix*CC + oc) = h;
        }
    }
}

// ---------------------------------------------------------------------------
// combine: h = sigmoid(U+bgU) * tanh(C+bc) -> f16 [z][pix][ch]  (iter 1)
// ---------------------------------------------------------------------------
__global__ __launch_bounds__(256)
void combine_kernel(const f16* __restrict__ Pg, const float* __restrict__ mask,
                    const float* __restrict__ bgU, const float* __restrict__ bc,
                    f16* __restrict__ outT, int n_l1)
{
    int z = blockIdx.y;
    int b = z / n_l1, l1 = z % n_l1;
    if (l1 != 0 && mask[b*LL + l1] == 0.f) return;
    int idx = blockIdx.x*256 + threadIdx.x;
    int pix = idx >> 2, cgq = idx & 3;
    size_t poff = (size_t)pix*CC + cgq*32;
    const f16* U = Pg + ((size_t)(0*(BB*LL) + z))*HW*CC + poff;
    const f16* C = Pg + ((size_t)(1*(BB*LL) + z))*HW*CC + poff;
    f16* dst = outT + (size_t)z*HW*CC + poff;
    for (int cg=0; cg<4; ++cg) {
        f16x8 u8 = *(const f16x8*)(U + cg*8);
        f16x8 c8 = *(const f16x8*)(C + cg*8);
        f16x8 o;
        #pragma unroll
        for (int j=0; j<8; ++j) {
            float uu = (float)u8[j] + bgU[cgq*32 + cg*8 + j];
            float cc = (float)c8[j] + bc[cgq*32 + cg*8 + j];
            float sig = 1.f/(1.f + expf(-uu));
            o[j] = (f16)(sig * tanhf(cc));
        }
        *(f16x8*)(dst + cg*8) = o;
    }
}

// ---------------------------------------------------------------------------
// mlp+combine (iter 2): h = sigmoid(U+bgU)*tanh(C+bc) inline from gate slabs
// (z = b; C slab at BB*LL + b), then out[b][oc][pix] = W h + bias.
// ---------------------------------------------------------------------------
__global__ __launch_bounds__(256)
void mlp_kernel(const f16* __restrict__ Pg, const float* __restrict__ bgU,
                const float* __restrict__ bc, const float* __restrict__ Wm,
                const float* __restrict__ bmlp, float* __restrict__ out)
{
    int b = blockIdx.z, oc0 = blockIdx.y*32;
    int pix = blockIdx.x*256 + threadIdx.x;
    size_t poff = (size_t)pix*CC;
    const f16* U = Pg + ((size_t)(0*(BB*LL) + b))*HW*CC + poff;
    const f16* C = Pg + ((size_t)(1*(BB*LL) + b))*HW*CC + poff;
    float acc[32];
    #pragma unroll
    for (int oc=0;oc<32;++oc) acc[oc]=0.f;
    for (int c8 = 0; c8 < 16; ++c8) {
        f16x8 u8 = *(const f16x8*)(U + c8*8);
        f16x8 g8 = *(const f16x8*)(C + c8*8);
        float f[8];
        #pragma unroll
        for (int j=0;j<8;++j) {
            float uu = (float)u8[j] + bgU[c8*8 + j];
            float cc = (float)g8[j] + bc[c8*8 + j];
            float sig = 1.f/(1.f + expf(-uu));
            f[j] = sig * tanhf(cc);
        }
        #pragma unroll
        for (int oc=0; oc<32; ++oc) {
            const float* w = Wm + (size_t)(oc0+oc)*CC + c8*8;
            #pragma unroll
            for (int j=0;j<8;++j) acc[oc] = fmaf(f[j], w[j], acc[oc]);
        }
    }
    #pragma unroll
    for (int oc=0;oc<32;++oc)
        out[((size_t)b*CC + oc0+oc)*HW + pix] = acc[oc] + bmlp[oc0+oc];
}

// ---------------------------------------------------------------------------
extern "C" void kernel_launch(void* const* d_in, const int* in_sizes, int n_in,
                              void* d_out, int out_size, void* d_ws, size_t ws_size,
                              hipStream_t stream)
{
    const float* x     = (const float*)d_in[0];
    const float* mask  = (const float*)d_in[1];
    const float* T     = (const float*)d_in[2];
    const int*   recl  = (const int*)  d_in[3];
    const float* Wmsg  = (const float*)d_in[4];
    const float* bmsg  = (const float*)d_in[5];
    const float* Wg    = (const float*)d_in[6];
    const float* bg    = (const float*)d_in[7];
    const float* Wc    = (const float*)d_in[8];
    const float* bc    = (const float*)d_in[9];
    const float* Wmlp  = (const float*)d_in[10];
    const float* bmlp  = (const float*)d_in[11];
    float* out = (float*)d_out;

    char* w = (char*)d_ws;
    f16*   xT   = (f16*)w;            w += (size_t)BB*LL*HW*CC*2;      // 17.3 MB
    float* fac  = (float*)w;          w += (size_t)32*HW*4;            // 1.1 MB
    f16*   WmF  = (f16*)w;            w += (size_t)9*128*256*2;
    f16*   WuF  = (f16*)w;            w += (size_t)9*128*256*2;
    f16*   WcF  = (f16*)w;            w += (size_t)9*128*256*2;
    f16*   Pm   = (f16*)w;            w += (size_t)40*HW*CC*2;         // 86.5 MB
    f16*   Pg   = (f16*)w;            w += (size_t)2*BB*LL*HW*CC*2;    // 34.6 MB
    f16*   aggT = (f16*)w;            w += (size_t)BB*LL*HW*CC*2;      // 17.3 MB
    f16*   f1T  = (f16*)w;            w += (size_t)BB*LL*HW*CC*2;      // 17.3 MB

    prep_kernel<<<4776, 256, 0, stream>>>(Wmsg, Wg, Wc, x, T, mask,
                                          WmF, WuF, WcF, xT, fac);

    // ---- iteration 1 (NM=4) ----
    msg_conv_kernel<4><<<dim3(66, 1, BB*LL*5), 256, 0, stream>>>(
        xT, T, fac, mask, recl, WmF, bmsg, Pm, LL);
    reduce_agg_kernel<<<dim3(132, BB*LL), 256, 0, stream>>>(Pm, mask, aggT, LL);
    gru_conv_kernel<4><<<dim3(66, 2, BB*LL), 256, 0, stream>>>(
        xT, aggT, mask, WuF, WcF, Pg, LL, 1);
    combine_kernel<<<dim3(132, BB*LL), 256, 0, stream>>>(
        Pg, mask, bg + CC, bc, f1T, LL);

    // ---- iteration 2 (NM=2 oc-split) ----
    msg_conv_kernel<2><<<dim3(66, 2, BB*5), 256, 0, stream>>>(
        f1T, T, fac, mask, recl, WmF, bmsg, Pm, 1);
    reduce_agg_kernel<<<dim3(132, BB), 256, 0, stream>>>(Pm, mask, aggT, 1);
    gru_conv_kernel<2><<<dim3(66, 4, BB), 256, 0, stream>>>(
        f1T, aggT, mask, WuF, WcF, Pg, 1, 2);

    // ---- final: combine(iter2) fused into MLP ----
    mlp_kernel<<<dim3(33, 4, BB), 256, 0, stream>>>(
        Pg, bg + CC, bc, Wmlp, bmlp, out);
}

// Round 19
// 424.021 us; speedup vs baseline: 1.3701x; 1.0838x over previous
//
#include <hip/hip_runtime.h>
#include <math.h>

#define BB 2
#define LL 4
#define CC 128
#define HH 48
#define WWID 176
#define HW 8448   // 48*176

typedef _Float16 f16;
typedef __attribute__((ext_vector_type(8))) _Float16 f16x8;
typedef __attribute__((ext_vector_type(4))) _Float16 f16x4;
typedef __attribute__((ext_vector_type(2))) _Float16 f16x2;
typedef __attribute__((ext_vector_type(4))) float f32x4;
typedef __attribute__((ext_vector_type(4))) unsigned int u32x4;

// inverse affine from a 4x4 pairwise T block
__device__ __forceinline__ void ainv_from(const float* __restrict__ t, float* a)
{
    float R00=t[0], R01=t[1], t0=t[3];
    float R10=t[4], R11=t[5], t1=t[7];
    float tx = t0 * 0.625f;              // / (RATIO*DS) = /1.6
    float ty = t1 * 0.625f;
    const float cx = WWID/2.0f, cy = HH/2.0f;
    float ftx = cx - (R00*cx + R01*cy) + tx;
    float fty = cy - (R10*cx + R11*cy) + ty;
    float det = R00*R11 - R01*R10;
    float inv = 1.0f/det;
    float i00 =  R11*inv, i01 = -R01*inv, i10 = -R10*inv, i11 = R00*inv;
    a[0]=i00; a[1]=i01; a[2]=-(i00*ftx + i01*fty);
    a[3]=i10; a[4]=i11; a[5]=-(i10*ftx + i11*fty);
}

// ---------------------------------------------------------------------------
// prep: one dispatch doing weight repack (fragment order), x->f16 transpose,
// and fac maps.  Block-id switch.
// ---------------------------------------------------------------------------
__global__ __launch_bounds__(256)
void prep_kernel(const float* __restrict__ Wm, const float* __restrict__ Wg,
                 const float* __restrict__ Wc, const float* __restrict__ x,
                 const float* __restrict__ T, const float* __restrict__ mask,
                 f16* __restrict__ WmF, f16* __restrict__ WuF, f16* __restrict__ WcF,
                 f16* __restrict__ xT, float* __restrict__ fac)
{
    int bid = blockIdx.x;
    int tid = threadIdx.x;
    if (bid < 3456) {
        int which = bid / 1152;
        const float* src = (which==0) ? Wm : (which==1) ? Wg : Wc;
        f16* dst         = (which==0) ? WmF : (which==1) ? WuF : WcF;
        int oc_off = (which==1) ? 128 : 0;
        int stride = (which==0) ? 256 : 384;
        int idx = (bid % 1152)*256 + tid;
        int j     = idx & 7;
        int hi    = (idx >> 3) & 3;
        int l15   = (idx >> 5) & 15;
        int ocblk = (idx >> 9) & 7;
        int kq    = (idx >> 12) & 7;
        int tap   = idx >> 15;
        int oc  = ocblk*16 + l15;
        int cin = kq*32 + hi*8 + j;
        dst[idx] = (f16)src[((size_t)(oc_off+oc)*stride + cin)*9 + tap];
    } else if (bid < 3720) {
        int g = bid - 3456;
        int bl = g / 33;
        int pix = (g % 33)*256 + tid;
        const float* src = x + (size_t)bl*CC*HW + pix;
        f16* dst = xT + (size_t)bl*HW*CC + (size_t)pix*CC;
        for (int gg = 0; gg < 8; ++gg) {
            f16x8 v0, v1;
            #pragma unroll
            for (int c2 = 0; c2 < 8; ++c2) {
                v0[c2] = (f16)src[(size_t)(gg*16 + c2    )*HW];
                v1[c2] = (f16)src[(size_t)(gg*16 + 8 + c2)*HW];
            }
            *(f16x8*)(dst + gg*16    ) = v0;
            *(f16x8*)(dst + gg*16 + 8) = v1;
        }
    } else {
        int g = bid - 3720;
        int slot = g / 33;                    // (b<<4)|(l2<<2)|l1
        int pix = (g % 33)*256 + tid;
        int b = slot >> 4, l2 = (slot >> 2) & 3;
        float mk = mask[b*LL + l2];
        float a[6];
        ainv_from(T + slot*16, a);
        float gx = (float)(pix % WWID), gy = (float)(pix / WWID);
        float sx = a[0]*gx + a[1]*gy + a[2];
        float sy = a[3]*gx + a[4]*gy + a[5];
        float x0 = floorf(sx), y0 = floorf(sy);
        float wx = sx-x0, wy = sy-y0;
        int xi=(int)x0, yi=(int)y0;
        bool vx0 = xi>=0 && xi<WWID, vx1 = xi+1>=0 && xi+1<WWID;
        bool vy0 = yi>=0 && yi<HH,   vy1 = yi+1>=0 && yi+1<HH;
        float r = (vx0&&vy0?(1.f-wx)*(1.f-wy):0.f) + (vx1&&vy0?wx*(1.f-wy):0.f)
                + (vx0&&vy1?(1.f-wx)*wy:0.f)       + (vx1&&vy1?wx*wy:0.f);
        fac[(size_t)slot*HW + pix] = r*mk;
    }
}

// ===========================================================================
// msg conv, templated on NM (4 = full block; 2 = oc-split via blockIdx.y).
// One JOB per block-z: z = (b, l1, src).  (round-17, proven)
// frag index = och*(2*NM) + wr*NM + m  (identical for the shipped NM values)
// ===========================================================================
template<int NM>
__global__ __launch_bounds__(256,3)
void msg_conv_kernel(const f16* __restrict__ featT, const float* __restrict__ T,
                     const float* __restrict__ fac, const float* __restrict__ mask,
                     const int* __restrict__ reclen,
                     const f16* __restrict__ WmF, const float* __restrict__ bm,
                     f16* __restrict__ Pm, int n_l1)
{
    int z = blockIdx.z;
    int b = z / (n_l1*5);
    int rem = z - b*(n_l1*5);
    int l1 = rem / 5, src = rem % 5;
    if (l1 != 0 && mask[b*LL + l1] == 0.f) return;   // output never consumed
    bool ego = (src == 4);
    int l2 = ego ? l1 : src;
    if (!ego && mask[b*LL + l2] == 0.f) return;      // sender inactive
    bool gather = (!ego) && (l2 != l1);
    int och = blockIdx.y;                            // 0 when grid.y==1

    int ty = blockIdx.x / 11, tx = blockIdx.x % 11;
    int y0 = ty*8, x0 = tx*16;
    int tid = threadIdx.x;
    int wid = tid >> 6, lane = tid & 63;
    int wr = wid >> 1, wc = wid & 1;
    int l15 = lane & 15, hi = lane >> 4;

    __shared__ short lt[180*128];        // 45 KB
    __shared__ float tw[4][192];
    __shared__ int   tof[4][192];

    const f16* in = featT + (size_t)(b*LL + l2)*HW*CC;

    if (gather) {
        float a6[6];
        ainv_from(T + ((b*LL + l2)*LL + l1)*16, a6);
        float a0=a6[0],a1=a6[1],a2=a6[2],a3=a6[3],a4=a6[4],a5=a6[5];
        for (int r = tid; r < 180; r += 256) {
            int yy = r / 18, xx = r - yy*18;
            int gy = y0 - 1 + yy, gx = x0 - 1 + xx;
            float w00=0.f,w10=0.f,w01=0.f,w11=0.f;
            int o00=0,o10=0,o01=0,o11=0;
            if (gy>=0 && gy<HH && gx>=0 && gx<WWID) {
                float sx = a0*(float)gx + a1*(float)gy + a2;
                float sy = a3*(float)gx + a4*(float)gy + a5;
                float xf = floorf(sx), yf = floorf(sy);
                float wx = sx-xf, wyv = sy-yf;
                int xi=(int)xf, yi=(int)yf;
                bool vx0=xi>=0&&xi<WWID, vx1=xi+1>=0&&xi+1<WWID;
                bool vy0=yi>=0&&yi<HH,   vy1=yi+1>=0&&yi+1<HH;
                int xc0=min(max(xi,0),WWID-1), xc1=min(max(xi+1,0),WWID-1);
                int yc0=min(max(yi,0),HH-1),   yc1=min(max(yi+1,0),HH-1);
                o00=(yc0*WWID+xc0)*CC; o10=(yc0*WWID+xc1)*CC;
                o01=(yc1*WWID+xc0)*CC; o11=(yc1*WWID+xc1)*CC;
                w00=(vx0&&vy0)?(1.f-wx)*(1.f-wyv):0.f;
                w10=(vx1&&vy0)?wx*(1.f-wyv):0.f;
                w01=(vx0&&vy1)?(1.f-wx)*wyv:0.f;
                w11=(vx1&&vy1)?wx*wyv:0.f;
            }
            tw[0][r]=w00; tw[1][r]=w10; tw[2][r]=w01; tw[3][r]=w11;
            tof[0][r]=o00; tof[1][r]=o10; tof[2][r]=o01; tof[3][r]=o11;
        }
        __syncthreads();
        for (int i = tid; i < 180*16; i += 256) {
            int row = i >> 4, cg = i & 15;
            f16 h00=(f16)tw[0][row], h10=(f16)tw[1][row];
            f16 h01=(f16)tw[2][row], h11=(f16)tw[3][row];
            f16x2 W00={h00,h00}, W10={h10,h10}, W01={h01,h01}, W11={h11,h11};
            int o00=tof[0][row], o10=tof[1][row], o01=tof[2][row], o11=tof[3][row];
            f16x8 t00 = *(const f16x8*)(in + o00 + cg*8);
            f16x8 t10 = *(const f16x8*)(in + o10 + cg*8);
            f16x8 t01 = *(const f16x8*)(in + o01 + cg*8);
            f16x8 t11 = *(const f16x8*)(in + o11 + cg*8);
            const f16x2* p00 = (const f16x2*)&t00;
            const f16x2* p10 = (const f16x2*)&t10;
            const f16x2* p01 = (const f16x2*)&t01;
            const f16x2* p11 = (const f16x2*)&t11;
            f16x8 outv;
            f16x2* po = (f16x2*)&outv;
            #pragma unroll
            for (int q=0;q<4;++q)
                po[q] = p00[q]*W00 + p10[q]*W10 + p01[q]*W01 + p11[q]*W11;
            int byte = row*256 + ((cg*16) ^ ((row&7)<<4));
            *(f16x8*)((char*)lt + byte) = outv;
        }
    } else {
        for (int i = tid; i < 180*16; i += 256) {
            int row = i >> 4, cg = i & 15;
            int yy = row / 18, xx = row - yy*18;
            int gy = y0 - 1 + yy, gx = x0 - 1 + xx;
            u32x4 val = {0,0,0,0};
            if (gy>=0 && gy<HH && gx>=0 && gx<WWID)
                val = *(const u32x4*)(in + (size_t)(gy*WWID+gx)*CC + cg*8);
            int byte = row*256 + ((cg*16) ^ ((row&7)<<4));
            *(u32x4*)((char*)lt + byte) = val;
        }
    }
    __syncthreads();

    f32x4 acc[NM][4];
    #pragma unroll
    for (int m=0;m<NM;++m)
        #pragma unroll
        for (int n=0;n<4;++n) acc[m][n] = (f32x4){0.f,0.f,0.f,0.f};

    const int kqbase = ego ? 4 : 0;
    const f16* wlane = WmF + l15*32 + hi*8;
    __builtin_amdgcn_s_setprio(1);
    for (int tap=0; tap<9; ++tap) {
        int dy = tap/3, dx = tap - dy*3;
        #pragma unroll
        for (int kk=0; kk<4; ++kk) {
            const f16* wt = wlane + (size_t)(((tap*8 + kqbase + kk)*8 + och*(2*NM) + wr*NM))*512;
            f16x8 av[NM];
            #pragma unroll
            for (int m=0;m<NM;++m)
                av[m] = *(const f16x8*)(wt + m*512);
            f16x8 bv[4];
            #pragma unroll
            for (int n=0;n<4;++n) {
                int pos = (wc*4 + n + dy)*18 + dx + l15;
                int byte = pos*256 + ((kk*64 + hi*16) ^ ((pos&7)<<4));
                bv[n] = *(const f16x8*)((const char*)lt + byte);
            }
            #pragma unroll
            for (int m=0;m<NM;++m)
                #pragma unroll
                for (int n=0;n<4;++n)
                    acc[m][n] = __builtin_amdgcn_mfma_f32_16x16x32_f16(
                        av[m], bv[n], acc[m][n], 0, 0, 0);
        }
    }
    __builtin_amdgcn_s_setprio(0);

    // per-pixel scale: fac (pair) or facsum (ego), times invrec (precision)
    float invrec = 1.0f / (float)reclen[b];
    float fsc[4];
    if (ego) {
        #pragma unroll
        for (int n=0;n<4;++n) fsc[n] = 0.f;
        for (int j=0;j<LL;++j) {
            if (mask[b*LL + j] == 0.f) continue;
            const float* fp = fac + (size_t)(b*16 + j*4 + l1)*HW;
            #pragma unroll
            for (int n=0;n<4;++n)
                fsc[n] += fp[(y0 + wc*4 + n)*WWID + x0 + l15];
        }
    } else {
        const float* fp = fac + (size_t)(b*16 + l2*4 + l1)*HW;
        #pragma unroll
        for (int n=0;n<4;++n)
            fsc[n] = fp[(y0 + wc*4 + n)*WWID + x0 + l15];
    }
    #pragma unroll
    for (int n=0;n<4;++n) fsc[n] *= invrec;

    f16* outp = Pm + (size_t)z*HW*CC;
    #pragma unroll
    for (int m=0;m<NM;++m) {
        int oc = (och*(2*NM) + wr*NM + m)*16 + hi*4;
        f32x4 b4 = {0.f,0.f,0.f,0.f};
        if (ego) b4 = *(const f32x4*)(bm + oc);
        #pragma unroll
        for (int n=0;n<4;++n) {
            int pix = (y0 + wc*4 + n)*WWID + x0 + l15;
            f32x4 v = (acc[m][n] + b4) * fsc[n];
            f16x4 h = {(f16)v[0], (f16)v[1], (f16)v[2], (f16)v[3]};
            *(f16x4*)(outp + (size_t)pix*CC + oc) = h;
        }
    }
}

// ---------------------------------------------------------------------------
// reduce: aggT[zi][pix][c] f16 = sum of active job slabs (invrec pre-folded)
// grid.x = 132; thread handles 32 channels of one pixel (fully coalesced).
// ---------------------------------------------------------------------------
__global__ __launch_bounds__(256)
void reduce_agg_kernel(const f16* __restrict__ Pm, const float* __restrict__ mask,
                       f16* __restrict__ aggT, int n_l1)
{
    int zi = blockIdx.y;                 // b*n_l1 + l1
    int b = zi / n_l1, l1 = zi % n_l1;
    if (l1 != 0 && mask[b*LL + l1] == 0.f) return;
    int idx = blockIdx.x*256 + threadIdx.x;   // 132*256 = 8448*4
    int pix = idx >> 2, cgq = idx & 3;
    bool act[4];
    #pragma unroll
    for (int j=0;j<LL;++j) act[j] = (mask[b*LL + j] != 0.f);
    size_t off = (size_t)pix*CC + cgq*32;
    const f16* base = Pm + (size_t)(zi*5)*HW*CC + off;
    f16* dst = aggT + (size_t)zi*HW*CC + off;
    for (int cg=0; cg<4; ++cg) {
        float s[8];
        f16x8 e = *(const f16x8*)(base + (size_t)4*HW*CC + cg*8);
        #pragma unroll
        for (int j8=0;j8<8;++j8) s[j8] = (float)e[j8];
        #pragma unroll
        for (int j=0;j<4;++j) {
            if (!act[j]) continue;
            f16x8 p = *(const f16x8*)(base + (size_t)j*HW*CC + cg*8);
            #pragma unroll
            for (int j8=0;j8<8;++j8) s[j8] += (float)p[j8];
        }
        f16x8 o;
        #pragma unroll
        for (int j8=0;j8<8;++j8) o[j8] = (f16)s[j8];
        *(f16x8*)(dst + cg*8) = o;
    }
}

// ===========================================================================
// gru conv DUAL-GATE, templated on NM = oc-fragments per wave PER GATE
// (NM=2: och in 0..1 -> 64 oc/block; NM=1: och in 0..3 -> 32 oc/block).
// Per kk-step: 2*NM A-loads feed 8*NM MFMA (4:1 ratio preserved).
// Full K=256 (stage feat; MFMA both gates; stage agg; MFMA both gates);
// epilogue: h = sigmoid(U+bgU)*tanh(C+bc) from fp32 accs -> f16 outT.
// No Pg slabs, no combine kernel.
// ===========================================================================
template<int NM>
__global__ __launch_bounds__(256,3)
void gru_conv_kernel(const f16* __restrict__ featT, const f16* __restrict__ aggT,
                     const float* __restrict__ mask,
                     const f16* __restrict__ WuF, const f16* __restrict__ WcF,
                     const float* __restrict__ bgU, const float* __restrict__ bc,
                     f16* __restrict__ outT, int n_l1)
{
    int z = blockIdx.z;
    int b = z / n_l1, l1 = z % n_l1;
    if (l1 != 0 && mask[b*LL + l1] == 0.f) return;
    int och = blockIdx.y;

    int ty = blockIdx.x / 11, tx = blockIdx.x % 11;
    int y0 = ty*8, x0 = tx*16;
    int tid = threadIdx.x;
    int wid = tid >> 6, lane = tid & 63;
    int wr = wid >> 1, wc = wid & 1;
    int l15 = lane & 15, hi = lane >> 4;

    __shared__ short lt[180*128];  // 45 KB

    f32x4 aU[NM][4], aC[NM][4];
    #pragma unroll
    for (int m=0;m<NM;++m)
        #pragma unroll
        for (int n=0;n<4;++n) {
            aU[m][n] = (f32x4){0.f,0.f,0.f,0.f};
            aC[m][n] = (f32x4){0.f,0.f,0.f,0.f};
        }

    const f16* wlaneU = WuF + l15*32 + hi*8;
    const f16* wlaneC = WcF + l15*32 + hi*8;

    for (int s = 0; s < 2; ++s) {
        const f16* in = (s==0) ? featT + (size_t)(b*LL + l1)*HW*CC
                               : aggT  + (size_t)(b*n_l1 + l1)*HW*CC;
        if (s) __syncthreads();           // MFMA readers of stage-0 done
        for (int i = tid; i < 180*16; i += 256) {
            int row = i >> 4, cg = i & 15;
            int yy = row / 18, xx = row - yy*18;
            int gy = y0 - 1 + yy, gx = x0 - 1 + xx;
            u32x4 val = {0,0,0,0};
            if (gy>=0 && gy<HH && gx>=0 && gx<WWID)
                val = *(const u32x4*)(in + (size_t)(gy*WWID+gx)*CC + cg*8);
            int byte = row*256 + ((cg*16) ^ ((row&7)<<4));
            *(u32x4*)((char*)lt + byte) = val;
        }
        __syncthreads();

        int kqbase = s*4;
        __builtin_amdgcn_s_setprio(1);
        for (int tap=0; tap<9; ++tap) {
            int dy = tap/3, dx = tap - dy*3;
            #pragma unroll
            for (int kk=0; kk<4; ++kk) {
                size_t blkoff = (size_t)(((tap*8 + kqbase + kk)*8 + och*(2*NM) + wr*NM))*512;
                f16x8 avU[NM], avC[NM];
                #pragma unroll
                for (int m=0;m<NM;++m) {
                    avU[m] = *(const f16x8*)(wlaneU + blkoff + m*512);
                    avC[m] = *(const f16x8*)(wlaneC + blkoff + m*512);
                }
                f16x8 bv[4];
                #pragma unroll
                for (int n=0;n<4;++n) {
                    int pos = (wc*4 + n + dy)*18 + dx + l15;
                    int byte = pos*256 + ((kk*64 + hi*16) ^ ((pos&7)<<4));
                    bv[n] = *(const f16x8*)((const char*)lt + byte);
                }
                #pragma unroll
                for (int m=0;m<NM;++m)
                    #pragma unroll
                    for (int n=0;n<4;++n) {
                        aU[m][n] = __builtin_amdgcn_mfma_f32_16x16x32_f16(
                            avU[m], bv[n], aU[m][n], 0, 0, 0);
                        aC[m][n] = __builtin_amdgcn_mfma_f32_16x16x32_f16(
                            avC[m], bv[n], aC[m][n], 0, 0, 0);
                    }
            }
        }
        __builtin_amdgcn_s_setprio(0);
    }

    f16* outp = outT + (size_t)z*HW*CC;
    #pragma unroll
    for (int m=0;m<NM;++m) {
        int oc = (och*(2*NM) + wr*NM + m)*16 + hi*4;
        f32x4 bu4 = *(const f32x4*)(bgU + oc);
        f32x4 bc4 = *(const f32x4*)(bc  + oc);
        #pragma unroll
        for (int n=0;n<4;++n) {
            int pix = (y0 + wc*4 + n)*WWID + x0 + l15;
            f32x4 u4 = aU[m][n] + bu4;
            f32x4 c4 = aC[m][n] + bc4;
            f16x4 h;
            #pragma unroll
            for (int j=0;j<4;++j) {
                float sig = 1.f/(1.f + expf(-u4[j]));
                h[j] = (f16)(sig * tanhf(c4[j]));
            }
            *(f16x4*)(outp + (size_t)pix*CC + oc) = h;
        }
    }
}

// ---------------------------------------------------------------------------
// final 1x1 MLP:  out[b][oc][pix] = sum_c f2T[b][pix][c]*W[oc][c] + bias
// ---------------------------------------------------------------------------
__global__ __launch_bounds__(256)
void mlp_kernel(const f16* __restrict__ feat2T, const float* __restrict__ Wm,
                const float* __restrict__ bmlp, float* __restrict__ out)
{
    int b = blockIdx.z, oc0 = blockIdx.y*32;
    int pix = blockIdx.x*256 + threadIdx.x;
    const f16* src = feat2T + (size_t)b*HW*CC + (size_t)pix*CC;
    float acc[32];
    #pragma unroll
    for (int oc=0;oc<32;++oc) acc[oc]=0.f;
    for (int c8 = 0; c8 < 16; ++c8) {
        f16x8 v = *(const f16x8*)(src + c8*8);
        float f[8];
        #pragma unroll
        for (int j=0;j<8;++j) f[j] = (float)v[j];
        #pragma unroll
        for (int oc=0; oc<32; ++oc) {
            const float* w = Wm + (size_t)(oc0+oc)*CC + c8*8;
            #pragma unroll
            for (int j=0;j<8;++j) acc[oc] = fmaf(f[j], w[j], acc[oc]);
        }
    }
    #pragma unroll
    for (int oc=0;oc<32;++oc)
        out[((size_t)b*CC + oc0+oc)*HW + pix] = acc[oc] + bmlp[oc0+oc];
}

// ---------------------------------------------------------------------------
extern "C" void kernel_launch(void* const* d_in, const int* in_sizes, int n_in,
                              void* d_out, int out_size, void* d_ws, size_t ws_size,
                              hipStream_t stream)
{
    const float* x     = (const float*)d_in[0];
    const float* mask  = (const float*)d_in[1];
    const float* T     = (const float*)d_in[2];
    const int*   recl  = (const int*)  d_in[3];
    const float* Wmsg  = (const float*)d_in[4];
    const float* bmsg  = (const float*)d_in[5];
    const float* Wg    = (const float*)d_in[6];
    const float* bg    = (const float*)d_in[7];
    const float* Wc    = (const float*)d_in[8];
    const float* bc    = (const float*)d_in[9];
    const float* Wmlp  = (const float*)d_in[10];
    const float* bmlp  = (const float*)d_in[11];
    float* out = (float*)d_out;

    char* w = (char*)d_ws;
    f16*   xT   = (f16*)w;            w += (size_t)BB*LL*HW*CC*2;      // 17.3 MB
    float* fac  = (float*)w;          w += (size_t)32*HW*4;            // 1.1 MB
    f16*   WmF  = (f16*)w;            w += (size_t)9*128*256*2;
    f16*   WuF  = (f16*)w;            w += (size_t)9*128*256*2;
    f16*   WcF  = (f16*)w;            w += (size_t)9*128*256*2;
    f16*   Pm   = (f16*)w;            w += (size_t)40*HW*CC*2;         // 86.5 MB
    f16*   aggT = (f16*)w;            w += (size_t)BB*LL*HW*CC*2;      // 17.3 MB
    f16*   f1T  = (f16*)w;            w += (size_t)BB*LL*HW*CC*2;      // 17.3 MB
    f16*   f2T  = (f16*)w;            w += (size_t)BB*HW*CC*2;         // 4.3 MB

    prep_kernel<<<4776, 256, 0, stream>>>(Wmsg, Wg, Wc, x, T, mask,
                                          WmF, WuF, WcF, xT, fac);

    // ---- iteration 1 ----
    msg_conv_kernel<4><<<dim3(66, 1, BB*LL*5), 256, 0, stream>>>(
        xT, T, fac, mask, recl, WmF, bmsg, Pm, LL);
    reduce_agg_kernel<<<dim3(132, BB*LL), 256, 0, stream>>>(Pm, mask, aggT, LL);
    gru_conv_kernel<2><<<dim3(66, 2, BB*LL), 256, 0, stream>>>(
        xT, aggT, mask, WuF, WcF, bg + CC, bc, f1T, LL);

    // ---- iteration 2 (only l1=0 consumed; NM halves again) ----
    msg_conv_kernel<2><<<dim3(66, 2, BB*5), 256, 0, stream>>>(
        f1T, T, fac, mask, recl, WmF, bmsg, Pm, 1);
    reduce_agg_kernel<<<dim3(132, BB), 256, 0, stream>>>(Pm, mask, aggT, 1);
    gru_conv_kernel<1><<<dim3(66, 4, BB), 256, 0, stream>>>(
        f1T, aggT, mask, WuF, WcF, bg + CC, bc, f2T, 1);

    // ---- final MLP ----
    mlp_kernel<<<dim3(33, 4, BB), 256, 0, stream>>>(f2T, Wmlp, bmlp, out);
}